// Round 5
// baseline (335.418 us; speedup 1.0000x reference)
//
#include <hip/hip_runtime.h>
#include <hip/hip_bf16.h>
#include <stdint.h>

#define BB_ 2
#define SS_ 2048
#define DIM_ 512
#define NH_ 8
#define QK_ 128
#define VD_ 128

typedef __attribute__((ext_vector_type(8))) short bf16x8;
typedef __attribute__((ext_vector_type(4))) float f32x4;
typedef __attribute__((ext_vector_type(8))) unsigned short ushort8;
typedef __attribute__((ext_vector_type(4))) unsigned short ushort4v;

__device__ __forceinline__ unsigned short f2bf(float f) {
  union { float f; unsigned int u; } v; v.f = f;
  unsigned int r = v.u + 0x7FFFu + ((v.u >> 16) & 1u);  // RNE
  return (unsigned short)(r >> 16);
}

__device__ __forceinline__ f32x4 mfma16(bf16x8 a, bf16x8 b, f32x4 c) {
  return __builtin_amdgcn_mfma_f32_16x16x32_bf16(a, b, c, 0, 0, 0);
}

// ---------------- convert / transpose kernels ----------------

__global__ void k_convert_x(const float* __restrict__ x, unsigned short* __restrict__ xb, int n4) {
  int i = blockIdx.x * blockDim.x + threadIdx.x;
  if (i < n4) {
    float4 v = reinterpret_cast<const float4*>(x)[i];
    ushort4v o;
    o[0] = f2bf(v.x); o[1] = f2bf(v.y); o[2] = f2bf(v.z); o[3] = f2bf(v.w);
    reinterpret_cast<ushort4v*>(xb)[i] = o;
  }
}

// src [R][C] fp32 -> dst [C][R] bf16 ; grid (C/64, R/64), block 256
__global__ void k_transpose_cvt(const float* __restrict__ src, unsigned short* __restrict__ dst,
                                int R, int C) {
  __shared__ float t[64][65];
  const int c0 = blockIdx.x * 64, r0 = blockIdx.y * 64;
  const int tid = threadIdx.x;
  const int rr = tid >> 4, cc4 = (tid & 15) * 4;
#pragma unroll
  for (int p = 0; p < 4; p++) {
    float4 v = *reinterpret_cast<const float4*>(src + (size_t)(r0 + rr + p * 16) * C + c0 + cc4);
    t[rr + p * 16][cc4 + 0] = v.x; t[rr + p * 16][cc4 + 1] = v.y;
    t[rr + p * 16][cc4 + 2] = v.z; t[rr + p * 16][cc4 + 3] = v.w;
  }
  __syncthreads();
  const int cl = tid >> 2, rb = (tid & 3) * 16;
#pragma unroll
  for (int g = 0; g < 2; g++) {
    ushort8 o;
#pragma unroll
    for (int j = 0; j < 8; j++) o[j] = f2bf(t[rb + g * 8 + j][cl]);
    *reinterpret_cast<ushort8*>(dst + (size_t)(c0 + cl) * R + r0 + rb + g * 8) = o;
  }
}

__global__ void k_concat_bias(const float* __restrict__ bq, const float* __restrict__ bk,
                              const float* __restrict__ bv, float* __restrict__ out) {
  int i = blockIdx.x * blockDim.x + threadIdx.x;
  if (i < 1024) out[i] = bq[i];
  else if (i < 2048) out[i] = bk[i - 1024];
  else if (i < 3072) out[i] = bv[i - 2048];
}

// ---------------- GEMM (A row-major [M][K], BT row-major [N][K], both bf16) ----------------

template <int EPI>
__global__ __launch_bounds__(256) void k_gemm_bt(
    const unsigned short* __restrict__ A, const unsigned short* __restrict__ BT,
    const float* __restrict__ bias, int K,
    unsigned short* __restrict__ oq, unsigned short* __restrict__ ok,
    unsigned short* __restrict__ ovt, float* __restrict__ of) {
  __shared__ __align__(16) unsigned short Al[128][48];
  __shared__ __align__(16) unsigned short Bl[128][48];
  const int tid = threadIdx.x;
  const int lane = tid & 63, wave = tid >> 6;
  const int wm = wave >> 1, wn = wave & 1;
  const int lr = lane & 15, lg = lane >> 4;
  const int m0 = blockIdx.y * 128, n0 = blockIdx.x * 128;
  f32x4 acc[4][4] = {};
  const int srow = tid >> 2, skc = (tid & 3) * 8;

  for (int k0 = 0; k0 < K; k0 += 32) {
    __syncthreads();
#pragma unroll
    for (int p = 0; p < 2; p++) {
      int row = srow + (p << 6);
      *reinterpret_cast<ushort8*>(&Al[row][skc]) =
          *reinterpret_cast<const ushort8*>(A + (size_t)(m0 + row) * K + k0 + skc);
      *reinterpret_cast<ushort8*>(&Bl[row][skc]) =
          *reinterpret_cast<const ushort8*>(BT + (size_t)(n0 + row) * K + k0 + skc);
    }
    __syncthreads();
    bf16x8 af[4], bfr[4];
#pragma unroll
    for (int i = 0; i < 4; i++)
      af[i] = *reinterpret_cast<const bf16x8*>(&Al[wm * 64 + i * 16 + lr][lg * 8]);
#pragma unroll
    for (int i = 0; i < 4; i++)
      bfr[i] = *reinterpret_cast<const bf16x8*>(&Bl[wn * 64 + i * 16 + lr][lg * 8]);
#pragma unroll
    for (int i = 0; i < 4; i++)
#pragma unroll
      for (int j = 0; j < 4; j++)
        acc[i][j] = mfma16(af[i], bfr[j], acc[i][j]);
  }

#pragma unroll
  for (int i = 0; i < 4; i++) {
#pragma unroll
    for (int j = 0; j < 4; j++) {
      const int n = n0 + wn * 64 + j * 16 + lr;
      const float bv = bias[n];
      const int mb = m0 + wm * 64 + i * 16 + lg * 4;
      if (EPI == 0) {
        const int region = n >> 10;
        const int h = (n & 1023) >> 7, d = n & 127;
        if (region == 2) {
          ushort4v pk;
#pragma unroll
          for (int r = 0; r < 4; r++) pk[r] = f2bf(acc[i][j][r] + bv);
          const int bb = mb >> 11, s = mb & 2047;
          *reinterpret_cast<ushort4v*>(ovt + ((size_t)((bb * NH_ + h) * VD_ + d)) * SS_ + s) = pk;
        } else {
          unsigned short* dst = (region == 0) ? oq : ok;
#pragma unroll
          for (int r = 0; r < 4; r++) {
            const int m = mb + r;
            const int bb = m >> 11, s = m & 2047;
            dst[((size_t)((bb * NH_ + h) * SS_ + s)) * QK_ + d] = f2bf(acc[i][j][r] + bv);
          }
        }
      } else {
#pragma unroll
        for (int r = 0; r < 4; r++) {
          const int m = mb + r;
          of[(size_t)m * DIM_ + n] = acc[i][j][r] + bv;
        }
      }
    }
  }
}

// ---------------- flash attention, S^T structure + in-block split-K ----------------
// grid (32, NH, B), block 512 = 8 waves. Waves 0-3: k-tiles [0,h0); waves 4-7:
// [h0,nkt) for the SAME 64 q-rows. One end barrier merges partials (exact).
// __launch_bounds__(512,2): 2 blocks/CU -> 128-VGPR cap -> no spill (R4 lesson:
// (512,4) forced 64 VGPR and spilled; spill traffic showed in FETCH/WRITE).

__global__ __launch_bounds__(512, 2) void k_attn(
    const unsigned short* __restrict__ q, const unsigned short* __restrict__ k,
    const unsigned short* __restrict__ vt, const float* __restrict__ pe,
    unsigned short* __restrict__ att) {
  __shared__ __align__(16) unsigned short P[8][16][72];    // 18 KB, wave-private
  __shared__ __align__(16) unsigned short Xo[4][16][132];  // 16.5 KB, half1 -> half0
  __shared__ float Xml[4][16][2];                          // 0.5 KB

  const int h = blockIdx.y, b = blockIdx.z;
  const int xi = (blockIdx.x + (blockIdx.z << 4)) & 31;
  const int qt = (xi < 16) ? xi : 47 - xi;  // same-CU (z-pair) blocks sum to 33 k-tiles

  const int lane = threadIdx.x & 63, wave = threadIdx.x >> 6;
  const int half = wave >> 2, sw = wave & 3;
  const int lr = lane & 15, lg = lane >> 4;
  const int qrow0 = qt * 64 + sw * 16;
  const int myq = qrow0 + lr;  // this lane's q-row (S^T/O^T layout)

  const unsigned short* qp = q + (size_t)(b * NH_ + h) * SS_ * QK_;
  const unsigned short* kp = k + (size_t)(b * NH_ + h) * SS_ * QK_;
  const unsigned short* vp = vt + (size_t)(b * NH_ + h) * VD_ * SS_;
  const float* pep = pe + (size_t)h * SS_ * SS_ + (size_t)myq * SS_;

  // Q fragments (reused every iteration)
  bf16x8 qf[4];
#pragma unroll
  for (int c = 0; c < 4; c++)
    qf[c] = *reinterpret_cast<const bf16x8*>(qp + (size_t)myq * QK_ + c * 32 + lg * 8);

  f32x4 o[8] = {};  // O^T frags: d = sub*16+lg*4+r, q = myq (unnormalized)
  float m = -1e30f, l = 0.f;
  const float scale = 0.08838834764831845f;  // 1/sqrt(128)

  const int nkt = qt + 1;
  const int h0 = (nkt + 1) >> 1;
  const int kt_lo = half ? h0 : 0;
  const int kt_hi = half ? nkt : h0;

  for (int kt = kt_lo; kt < kt_hi; kt++) {
    const int kbase = kt * 64;

    // V^T fragments, issued first
    bf16x8 vf[2][8];
#pragma unroll
    for (int kk = 0; kk < 2; kk++)
#pragma unroll
      for (int sub = 0; sub < 8; sub++)
        vf[kk][sub] = *reinterpret_cast<const bf16x8*>(
            vp + (size_t)(sub * 16 + lr) * SS_ + kbase + kk * 32 + lg * 8);

    // pe: 4 contiguous float4 per lane (k fast axis)
    f32x4 pe4[4];
#pragma unroll
    for (int ck = 0; ck < 4; ck++)
      pe4[ck] = *reinterpret_cast<const f32x4*>(pep + kbase + ck * 16 + lg * 4);

    // S^T = K * Q^T : sc[ck][r] = S[myq][kbase + ck*16 + lg*4 + r]
    f32x4 sc[4];
#pragma unroll
    for (int ck = 0; ck < 4; ck++) {
      f32x4 a = {};
#pragma unroll
      for (int c = 0; c < 4; c++) {
        const bf16x8 kf = *reinterpret_cast<const bf16x8*>(
            kp + (size_t)(kbase + ck * 16 + lr) * QK_ + c * 32 + lg * 8);
        a = mfma16(kf, qf[c], a);
      }
      sc[ck] = a;
    }

    // scale + pe + causal (diag tile only), in-lane max
    const bool diag = (kt == qt);
    float tm = -1e30f;
#pragma unroll
    for (int ck = 0; ck < 4; ck++) {
#pragma unroll
      for (int r = 0; r < 4; r++) {
        float v = fmaf(sc[ck][r], scale, pe4[ck][r]);
        if (diag && (kbase + ck * 16 + lg * 4 + r) > myq) v = -1e30f;
        sc[ck][r] = v;
        tm = fmaxf(tm, v);
      }
    }
    tm = fmaxf(tm, __shfl_xor(tm, 16));
    tm = fmaxf(tm, __shfl_xor(tm, 32));

    const float mnew = fmaxf(m, tm);
    const float ps = __expf(m - mnew);
    m = mnew;
    float rsum = 0.f;
#pragma unroll
    for (int ck = 0; ck < 4; ck++)
#pragma unroll
      for (int r = 0; r < 4; r++) {
        const float p = __expf(sc[ck][r] - mnew);
        sc[ck][r] = p;
        rsum += p;
      }
    rsum += __shfl_xor(rsum, 16);
    rsum += __shfl_xor(rsum, 32);
    l = l * ps + rsum;
#pragma unroll
    for (int sub = 0; sub < 8; sub++)
#pragma unroll
      for (int r = 0; r < 4; r++) o[sub][r] *= ps;

    // P^T -> wave-private LDS
#pragma unroll
    for (int ck = 0; ck < 4; ck++) {
      ushort4v pk;
#pragma unroll
      for (int r = 0; r < 4; r++) pk[r] = f2bf(sc[ck][r]);
      *reinterpret_cast<ushort4v*>(&P[wave][lr][ck * 16 + lg * 4]) = pk;
    }

    // PV: O^T[d][q] += V^T-frag * P^T-frag
#pragma unroll
    for (int kk = 0; kk < 2; kk++) {
      const bf16x8 pf = *reinterpret_cast<const bf16x8*>(&P[wave][lr][kk * 32 + lg * 8]);
#pragma unroll
      for (int sub = 0; sub < 8; sub++)
        o[sub] = mfma16(vf[kk][sub], pf, o[sub]);
    }
  }

  // half1: publish normalized partial (o/l, m, l) to LDS
  if (half) {
    const float inv = (l > 0.f) ? 1.0f / l : 0.f;
#pragma unroll
    for (int sub = 0; sub < 8; sub++) {
      ushort4v pk;
#pragma unroll
      for (int r = 0; r < 4; r++) pk[r] = f2bf(o[sub][r] * inv);
      *reinterpret_cast<ushort4v*>(&Xo[sw][lr][sub * 16 + lg * 4]) = pk;
    }
    if (lg == 0) { Xml[sw][lr][0] = m; Xml[sw][lr][1] = l; }
  }
  __syncthreads();
  // half0: merge and write
  if (!half) {
    const float m1 = Xml[sw][lr][0], l1 = Xml[sw][lr][1];
    const float ms = fmaxf(m, m1);
    const float w0 = __expf(m - ms);         // applies to unnormalized o
    const float c0 = w0 * l;
    const float c1 = __expf(m1 - ms) * l1;
    const float invT = 1.0f / (c0 + c1);
    unsigned short* ob = att + (size_t)(b * SS_ + myq) * (NH_ * VD_) + h * VD_;
#pragma unroll
    for (int sub = 0; sub < 8; sub++) {
      const ushort4v o1 = *reinterpret_cast<const ushort4v*>(&Xo[sw][lr][sub * 16 + lg * 4]);
      ushort4v pk;
#pragma unroll
      for (int r = 0; r < 4; r++) {
        union { unsigned int u; float f; } cv; cv.u = ((unsigned int)o1[r]) << 16;
        pk[r] = f2bf((w0 * o[sub][r] + c1 * cv.f) * invT);
      }
      *reinterpret_cast<ushort4v*>(ob + sub * 16 + lg * 4) = pk;
    }
  }
}

// ---------------- launcher ----------------

extern "C" void kernel_launch(void* const* d_in, const int* in_sizes, int n_in,
                              void* d_out, int out_size, void* d_ws, size_t ws_size,
                              hipStream_t stream) {
  const float* x    = (const float*)d_in[0];
  const float* pe   = (const float*)d_in[3];
  const float* wq_w = (const float*)d_in[4];
  const float* wq_b = (const float*)d_in[5];
  const float* wk_w = (const float*)d_in[6];
  const float* wk_b = (const float*)d_in[7];
  const float* wv_w = (const float*)d_in[8];
  const float* wv_b = (const float*)d_in[9];
  const float* wo_w = (const float*)d_in[10];
  const float* wo_b = (const float*)d_in[11];
  float* out = (float*)d_out;

  char* ws = (char*)d_ws;
  unsigned short* x_bf   = (unsigned short*)(ws);                 // 4 MB
  unsigned short* wqkv_t = (unsigned short*)(ws + 4194304);       // 3 MB
  unsigned short* wo_t   = (unsigned short*)(ws + 7340032);       // 1 MB
  float*          qkv_b  = (float*)(ws + 8388608);                // 12 KB
  unsigned short* qb     = (unsigned short*)(ws + 8400896);       // 8 MB
  unsigned short* kb     = (unsigned short*)(ws + 16789504);      // 8 MB
  unsigned short* vtb    = (unsigned short*)(ws + 25178112);      // 8 MB
  unsigned short* attb   = (unsigned short*)(ws + 33566720);      // 8 MB

  k_convert_x<<<2048, 256, 0, stream>>>(x, x_bf, (4096 * 512) / 4);
  {
    dim3 gt(16, 8);  // C=1024, R=512
    k_transpose_cvt<<<gt, 256, 0, stream>>>(wq_w, wqkv_t, 512, 1024);
    k_transpose_cvt<<<gt, 256, 0, stream>>>(wk_w, wqkv_t + 1024 * 512, 512, 1024);
    k_transpose_cvt<<<gt, 256, 0, stream>>>(wv_w, wqkv_t + 2048 * 512, 512, 1024);
    dim3 gt2(8, 16);  // C=512, R=1024
    k_transpose_cvt<<<gt2, 256, 0, stream>>>(wo_w, wo_t, 1024, 512);
  }
  k_concat_bias<<<12, 256, 0, stream>>>(wq_b, wk_b, wv_b, qkv_b);

  dim3 g1(24, 32);
  k_gemm_bt<0><<<g1, 256, 0, stream>>>(x_bf, wqkv_t, qkv_b, 512, qb, kb, vtb, nullptr);

  dim3 g2(32, NH_, BB_);
  k_attn<<<g2, 512, 0, stream>>>(qb, kb, vtb, pe, attb);

  dim3 g3(4, 32);
  k_gemm_bt<1><<<g3, 256, 0, stream>>>(attb, wo_t, wo_b, 1024, nullptr, nullptr, nullptr, out);
}

// Round 6
// 259.945 us; speedup vs baseline: 1.2903x; 1.2903x over previous
//
#include <hip/hip_runtime.h>
#include <hip/hip_bf16.h>
#include <stdint.h>

#define BB_ 2
#define SS_ 2048
#define DIM_ 512
#define NH_ 8
#define QK_ 128
#define VD_ 128

typedef __attribute__((ext_vector_type(8))) short bf16x8;
typedef __attribute__((ext_vector_type(4))) float f32x4;
typedef __attribute__((ext_vector_type(8))) unsigned short ushort8;
typedef __attribute__((ext_vector_type(4))) unsigned short ushort4v;

__device__ __forceinline__ unsigned short f2bf(float f) {
  union { float f; unsigned int u; } v; v.f = f;
  unsigned int r = v.u + 0x7FFFu + ((v.u >> 16) & 1u);  // RNE
  return (unsigned short)(r >> 16);
}

__device__ __forceinline__ f32x4 mfma16(bf16x8 a, bf16x8 b, f32x4 c) {
  return __builtin_amdgcn_mfma_f32_16x16x32_bf16(a, b, c, 0, 0, 0);
}

// ---------------- convert / transpose kernels ----------------

__global__ void k_convert_x(const float* __restrict__ x, unsigned short* __restrict__ xb, int n4) {
  int i = blockIdx.x * blockDim.x + threadIdx.x;
  if (i < n4) {
    float4 v = reinterpret_cast<const float4*>(x)[i];
    ushort4v o;
    o[0] = f2bf(v.x); o[1] = f2bf(v.y); o[2] = f2bf(v.z); o[3] = f2bf(v.w);
    reinterpret_cast<ushort4v*>(xb)[i] = o;
  }
}

// src [R][C] fp32 -> dst [C][R] bf16 ; grid (C/64, R/64), block 256
__global__ void k_transpose_cvt(const float* __restrict__ src, unsigned short* __restrict__ dst,
                                int R, int C) {
  __shared__ float t[64][65];
  const int c0 = blockIdx.x * 64, r0 = blockIdx.y * 64;
  const int tid = threadIdx.x;
  const int rr = tid >> 4, cc4 = (tid & 15) * 4;
#pragma unroll
  for (int p = 0; p < 4; p++) {
    float4 v = *reinterpret_cast<const float4*>(src + (size_t)(r0 + rr + p * 16) * C + c0 + cc4);
    t[rr + p * 16][cc4 + 0] = v.x; t[rr + p * 16][cc4 + 1] = v.y;
    t[rr + p * 16][cc4 + 2] = v.z; t[rr + p * 16][cc4 + 3] = v.w;
  }
  __syncthreads();
  const int cl = tid >> 2, rb = (tid & 3) * 16;
#pragma unroll
  for (int g = 0; g < 2; g++) {
    ushort8 o;
#pragma unroll
    for (int j = 0; j < 8; j++) o[j] = f2bf(t[rb + g * 8 + j][cl]);
    *reinterpret_cast<ushort8*>(dst + (size_t)(c0 + cl) * R + r0 + rb + g * 8) = o;
  }
}

__global__ void k_concat_bias(const float* __restrict__ bq, const float* __restrict__ bk,
                              const float* __restrict__ bv, float* __restrict__ out) {
  int i = blockIdx.x * blockDim.x + threadIdx.x;
  if (i < 1024) out[i] = bq[i];
  else if (i < 2048) out[i] = bk[i - 1024];
  else if (i < 3072) out[i] = bv[i - 2048];
}

// ---------------- GEMM (A row-major [M][K], BT row-major [N][K], both bf16) ----------------
// EPI=0: QKV epilogue. q is PRE-SCALED by 1/sqrt(128) so attention needs no scale.

template <int EPI>
__global__ __launch_bounds__(256) void k_gemm_bt(
    const unsigned short* __restrict__ A, const unsigned short* __restrict__ BT,
    const float* __restrict__ bias, int K,
    unsigned short* __restrict__ oq, unsigned short* __restrict__ ok,
    unsigned short* __restrict__ ovt, float* __restrict__ of) {
  __shared__ __align__(16) unsigned short Al[128][48];
  __shared__ __align__(16) unsigned short Bl[128][48];
  const int tid = threadIdx.x;
  const int lane = tid & 63, wave = tid >> 6;
  const int wm = wave >> 1, wn = wave & 1;
  const int lr = lane & 15, lg = lane >> 4;
  const int m0 = blockIdx.y * 128, n0 = blockIdx.x * 128;
  f32x4 acc[4][4] = {};
  const int srow = tid >> 2, skc = (tid & 3) * 8;

  for (int k0 = 0; k0 < K; k0 += 32) {
    __syncthreads();
#pragma unroll
    for (int p = 0; p < 2; p++) {
      int row = srow + (p << 6);
      *reinterpret_cast<ushort8*>(&Al[row][skc]) =
          *reinterpret_cast<const ushort8*>(A + (size_t)(m0 + row) * K + k0 + skc);
      *reinterpret_cast<ushort8*>(&Bl[row][skc]) =
          *reinterpret_cast<const ushort8*>(BT + (size_t)(n0 + row) * K + k0 + skc);
    }
    __syncthreads();
    bf16x8 af[4], bfr[4];
#pragma unroll
    for (int i = 0; i < 4; i++)
      af[i] = *reinterpret_cast<const bf16x8*>(&Al[wm * 64 + i * 16 + lr][lg * 8]);
#pragma unroll
    for (int i = 0; i < 4; i++)
      bfr[i] = *reinterpret_cast<const bf16x8*>(&Bl[wn * 64 + i * 16 + lr][lg * 8]);
#pragma unroll
    for (int i = 0; i < 4; i++)
#pragma unroll
      for (int j = 0; j < 4; j++)
        acc[i][j] = mfma16(af[i], bfr[j], acc[i][j]);
  }

#pragma unroll
  for (int i = 0; i < 4; i++) {
#pragma unroll
    for (int j = 0; j < 4; j++) {
      const int n = n0 + wn * 64 + j * 16 + lr;
      const float bv = bias[n];
      const int mb = m0 + wm * 64 + i * 16 + lg * 4;
      if (EPI == 0) {
        const int region = n >> 10;
        const int h = (n & 1023) >> 7, d = n & 127;
        if (region == 2) {
          ushort4v pk;
#pragma unroll
          for (int r = 0; r < 4; r++) pk[r] = f2bf(acc[i][j][r] + bv);
          const int bb = mb >> 11, s = mb & 2047;
          *reinterpret_cast<ushort4v*>(ovt + ((size_t)((bb * NH_ + h) * VD_ + d)) * SS_ + s) = pk;
        } else {
          unsigned short* dst = (region == 0) ? oq : ok;
          const float qs = (region == 0) ? 0.08838834764831845f : 1.0f;  // pre-scale q
#pragma unroll
          for (int r = 0; r < 4; r++) {
            const int m = mb + r;
            const int bb = m >> 11, s = m & 2047;
            dst[((size_t)((bb * NH_ + h) * SS_ + s)) * QK_ + d] = f2bf((acc[i][j][r] + bv) * qs);
          }
        }
      } else {
#pragma unroll
        for (int r = 0; r < 4; r++) {
          const int m = mb + r;
          of[(size_t)m * DIM_ + n] = acc[i][j][r] + bv;
        }
      }
    }
  }
}

// ---------------- flash attention: 2-wave blocks, split-K, S^T structure ----------------
// grid (128, NH, B), block 128 = 2 waves; block owns 16 q-rows (tile rt).
// Wave0: k-tiles [0,h0), wave1: [h0,nkt); exact online-softmax merge via LDS.
// pe is loaded directly as the QK^T MFMA C-operand (q pre-scaled by 1/sqrt(128)).
// ~115 regs -> 4 waves/SIMD (launch_bounds(128,4)); 4096 waves fill the machine.

__global__ __launch_bounds__(128, 4) void k_attn(
    const unsigned short* __restrict__ q, const unsigned short* __restrict__ k,
    const unsigned short* __restrict__ vt, const float* __restrict__ pe,
    unsigned short* __restrict__ att) {
  __shared__ __align__(16) unsigned short P[2][16][72];   // 4.5 KB, wave-private
  __shared__ __align__(16) unsigned short Xo[16][132];    // 4.1 KB, wave1 -> wave0
  __shared__ float Xml[16][2];

  const int h = blockIdx.y, b = blockIdx.z;
  // balance: same-CU blocks (linear-id stride 256) get well-mixed k-lengths
  const int rt = (127 - (int)blockIdx.x + 16 * (h + 8 * b)) & 127;

  const int lane = threadIdx.x & 63, wave = threadIdx.x >> 6;
  const int lr = lane & 15, lg = lane >> 4;
  const int myq = rt * 16 + lr;  // this lane's q-row (S^T/O^T layout)

  const unsigned short* qp = q + (size_t)(b * NH_ + h) * SS_ * QK_;
  const unsigned short* kp = k + (size_t)(b * NH_ + h) * SS_ * QK_;
  const unsigned short* vp = vt + (size_t)(b * NH_ + h) * VD_ * SS_;
  const float* pep = pe + (size_t)h * SS_ * SS_ + (size_t)myq * SS_;

  // Q fragments (pre-scaled), reused every iteration
  bf16x8 qf[4];
#pragma unroll
  for (int c = 0; c < 4; c++)
    qf[c] = *reinterpret_cast<const bf16x8*>(qp + (size_t)myq * QK_ + c * 32 + lg * 8);

  f32x4 o[8] = {};  // O^T frags: d = sub*16+lg*4+r, q = myq (unnormalized)
  float m = -1e30f, l = 0.f;

  const int nkt = (rt >> 2) + 1;
  const int h0 = (nkt + 1) >> 1;
  const int kt_lo = wave ? h0 : 0;
  const int kt_hi = wave ? nkt : h0;

  for (int kt = kt_lo; kt < kt_hi; kt++) {
    const int kbase = kt * 64;

    // V^T fragments for kk=0, issued first
    bf16x8 vf[8];
#pragma unroll
    for (int sub = 0; sub < 8; sub++)
      vf[sub] = *reinterpret_cast<const bf16x8*>(
          vp + (size_t)(sub * 16 + lr) * SS_ + kbase + lg * 8);

    // S^T = K*Q^T + pe : C-operand initialized from pe (contiguous float4 loads)
    f32x4 sc[4];
#pragma unroll
    for (int ck = 0; ck < 4; ck++)
      sc[ck] = *reinterpret_cast<const f32x4*>(pep + kbase + ck * 16 + lg * 4);
#pragma unroll
    for (int ck = 0; ck < 4; ck++) {
#pragma unroll
      for (int c = 0; c < 4; c++) {
        const bf16x8 kf = *reinterpret_cast<const bf16x8*>(
            kp + (size_t)(kbase + ck * 16 + lr) * QK_ + c * 32 + lg * 8);
        sc[ck] = mfma16(kf, qf[c], sc[ck]);
      }
    }

    // causal mask (only the last tile of this q-row range touches the diagonal)
    const bool diag = (kt == nkt - 1);
    float tm = -1e30f;
#pragma unroll
    for (int ck = 0; ck < 4; ck++) {
#pragma unroll
      for (int r = 0; r < 4; r++) {
        float v = sc[ck][r];
        if (diag && (kbase + ck * 16 + lg * 4 + r) > myq) v = -1e30f;
        sc[ck][r] = v;
        tm = fmaxf(tm, v);
      }
    }
    tm = fmaxf(tm, __shfl_xor(tm, 16));
    tm = fmaxf(tm, __shfl_xor(tm, 32));

    const float mnew = fmaxf(m, tm);
    const float ps = __expf(m - mnew);
    m = mnew;
    float rsum = 0.f;
#pragma unroll
    for (int ck = 0; ck < 4; ck++)
#pragma unroll
      for (int r = 0; r < 4; r++) {
        const float p = __expf(sc[ck][r] - mnew);
        sc[ck][r] = p;
        rsum += p;
      }
    rsum += __shfl_xor(rsum, 16);
    rsum += __shfl_xor(rsum, 32);
    l = l * ps + rsum;
#pragma unroll
    for (int sub = 0; sub < 8; sub++)
#pragma unroll
      for (int r = 0; r < 4; r++) o[sub][r] *= ps;

    // P^T -> wave-private LDS
#pragma unroll
    for (int ck = 0; ck < 4; ck++) {
      ushort4v pk;
#pragma unroll
      for (int r = 0; r < 4; r++) pk[r] = f2bf(sc[ck][r]);
      *reinterpret_cast<ushort4v*>(&P[wave][lr][ck * 16 + lg * 4]) = pk;
    }

    // PV kk=0
    {
      const bf16x8 pf = *reinterpret_cast<const bf16x8*>(&P[wave][lr][lg * 8]);
#pragma unroll
      for (int sub = 0; sub < 8; sub++)
        o[sub] = mfma16(vf[sub], pf, o[sub]);
    }
    // V^T fragments kk=1 (reuse regs), PV kk=1
#pragma unroll
    for (int sub = 0; sub < 8; sub++)
      vf[sub] = *reinterpret_cast<const bf16x8*>(
          vp + (size_t)(sub * 16 + lr) * SS_ + kbase + 32 + lg * 8);
    {
      const bf16x8 pf = *reinterpret_cast<const bf16x8*>(&P[wave][lr][32 + lg * 8]);
#pragma unroll
      for (int sub = 0; sub < 8; sub++)
        o[sub] = mfma16(vf[sub], pf, o[sub]);
    }
  }

  // wave1: publish normalized partial (o/l, m, l)
  if (wave) {
    const float inv = (l > 0.f) ? 1.0f / l : 0.f;
#pragma unroll
    for (int sub = 0; sub < 8; sub++) {
      ushort4v pk;
#pragma unroll
      for (int r = 0; r < 4; r++) pk[r] = f2bf(o[sub][r] * inv);
      *reinterpret_cast<ushort4v*>(&Xo[lr][sub * 16 + lg * 4]) = pk;
    }
    if (lg == 0) { Xml[lr][0] = m; Xml[lr][1] = l; }
  }
  __syncthreads();
  // wave0: merge and write
  if (!wave) {
    const float m1 = Xml[lr][0], l1 = Xml[lr][1];
    const float ms = fmaxf(m, m1);
    const float w0 = __expf(m - ms);         // applies to unnormalized o
    const float c0 = w0 * l;
    const float c1 = __expf(m1 - ms) * l1;
    const float invT = 1.0f / (c0 + c1);
    unsigned short* ob = att + (size_t)(b * SS_ + myq) * (NH_ * VD_) + h * VD_;
#pragma unroll
    for (int sub = 0; sub < 8; sub++) {
      const ushort4v o1 = *reinterpret_cast<const ushort4v*>(&Xo[lr][sub * 16 + lg * 4]);
      ushort4v pk;
#pragma unroll
      for (int r = 0; r < 4; r++) {
        union { unsigned int u; float f; } cv; cv.u = ((unsigned int)o1[r]) << 16;
        pk[r] = f2bf((w0 * o[sub][r] + c1 * cv.f) * invT);
      }
      *reinterpret_cast<ushort4v*>(ob + sub * 16 + lg * 4) = pk;
    }
  }
}

// ---------------- launcher ----------------

extern "C" void kernel_launch(void* const* d_in, const int* in_sizes, int n_in,
                              void* d_out, int out_size, void* d_ws, size_t ws_size,
                              hipStream_t stream) {
  const float* x    = (const float*)d_in[0];
  const float* pe   = (const float*)d_in[3];
  const float* wq_w = (const float*)d_in[4];
  const float* wq_b = (const float*)d_in[5];
  const float* wk_w = (const float*)d_in[6];
  const float* wk_b = (const float*)d_in[7];
  const float* wv_w = (const float*)d_in[8];
  const float* wv_b = (const float*)d_in[9];
  const float* wo_w = (const float*)d_in[10];
  const float* wo_b = (const float*)d_in[11];
  float* out = (float*)d_out;

  char* ws = (char*)d_ws;
  unsigned short* x_bf   = (unsigned short*)(ws);                 // 4 MB
  unsigned short* wqkv_t = (unsigned short*)(ws + 4194304);       // 3 MB
  unsigned short* wo_t   = (unsigned short*)(ws + 7340032);       // 1 MB
  float*          qkv_b  = (float*)(ws + 8388608);                // 12 KB
  unsigned short* qb     = (unsigned short*)(ws + 8400896);       // 8 MB
  unsigned short* kb     = (unsigned short*)(ws + 16789504);      // 8 MB
  unsigned short* vtb    = (unsigned short*)(ws + 25178112);      // 8 MB
  unsigned short* attb   = (unsigned short*)(ws + 33566720);      // 8 MB

  k_convert_x<<<2048, 256, 0, stream>>>(x, x_bf, (4096 * 512) / 4);
  {
    dim3 gt(16, 8);  // C=1024, R=512
    k_transpose_cvt<<<gt, 256, 0, stream>>>(wq_w, wqkv_t, 512, 1024);
    k_transpose_cvt<<<gt, 256, 0, stream>>>(wk_w, wqkv_t + 1024 * 512, 512, 1024);
    k_transpose_cvt<<<gt, 256, 0, stream>>>(wv_w, wqkv_t + 2048 * 512, 512, 1024);
    dim3 gt2(8, 16);  // C=512, R=1024
    k_transpose_cvt<<<gt2, 256, 0, stream>>>(wo_w, wo_t, 1024, 512);
  }
  k_concat_bias<<<12, 256, 0, stream>>>(wq_b, wk_b, wv_b, qkv_b);

  dim3 g1(24, 32);
  k_gemm_bt<0><<<g1, 256, 0, stream>>>(x_bf, wqkv_t, qkv_b, 512, qb, kb, vtb, nullptr);

  dim3 g2(128, NH_, BB_);
  k_attn<<<g2, 128, 0, stream>>>(qb, kb, vtb, pe, attb);

  dim3 g3(4, 32);
  k_gemm_bt<1><<<g3, 256, 0, stream>>>(attb, wo_t, wo_b, 1024, nullptr, nullptr, nullptr, out);
}

// Round 7
// 232.866 us; speedup vs baseline: 1.4404x; 1.1163x over previous
//
#include <hip/hip_runtime.h>
#include <hip/hip_bf16.h>
#include <stdint.h>

#define BB_ 2
#define SS_ 2048
#define DIM_ 512
#define NH_ 8
#define QK_ 128
#define VD_ 128

typedef __attribute__((ext_vector_type(8))) short bf16x8;
typedef __attribute__((ext_vector_type(4))) float f32x4;
typedef __attribute__((ext_vector_type(8))) unsigned short ushort8;
typedef __attribute__((ext_vector_type(4))) unsigned short ushort4v;

__device__ __forceinline__ unsigned short f2bf(float f) {
  union { float f; unsigned int u; } v; v.f = f;
  unsigned int r = v.u + 0x7FFFu + ((v.u >> 16) & 1u);  // RNE
  return (unsigned short)(r >> 16);
}

__device__ __forceinline__ f32x4 mfma16(bf16x8 a, bf16x8 b, f32x4 c) {
  return __builtin_amdgcn_mfma_f32_16x16x32_bf16(a, b, c, 0, 0, 0);
}

// ---------------- convert / transpose kernels ----------------

__global__ void k_convert_x(const float* __restrict__ x, unsigned short* __restrict__ xb, int n4) {
  int i = blockIdx.x * blockDim.x + threadIdx.x;
  if (i < n4) {
    float4 v = reinterpret_cast<const float4*>(x)[i];
    ushort4v o;
    o[0] = f2bf(v.x); o[1] = f2bf(v.y); o[2] = f2bf(v.z); o[3] = f2bf(v.w);
    reinterpret_cast<ushort4v*>(xb)[i] = o;
  }
}

// src [R][C] fp32 -> dst [C][R] bf16 ; grid (C/64, R/64), block 256
__global__ void k_transpose_cvt(const float* __restrict__ src, unsigned short* __restrict__ dst,
                                int R, int C) {
  __shared__ float t[64][65];
  const int c0 = blockIdx.x * 64, r0 = blockIdx.y * 64;
  const int tid = threadIdx.x;
  const int rr = tid >> 4, cc4 = (tid & 15) * 4;
#pragma unroll
  for (int p = 0; p < 4; p++) {
    float4 v = *reinterpret_cast<const float4*>(src + (size_t)(r0 + rr + p * 16) * C + c0 + cc4);
    t[rr + p * 16][cc4 + 0] = v.x; t[rr + p * 16][cc4 + 1] = v.y;
    t[rr + p * 16][cc4 + 2] = v.z; t[rr + p * 16][cc4 + 3] = v.w;
  }
  __syncthreads();
  const int cl = tid >> 2, rb = (tid & 3) * 16;
#pragma unroll
  for (int g = 0; g < 2; g++) {
    ushort8 o;
#pragma unroll
    for (int j = 0; j < 8; j++) o[j] = f2bf(t[rb + g * 8 + j][cl]);
    *reinterpret_cast<ushort8*>(dst + (size_t)(c0 + cl) * R + r0 + rb + g * 8) = o;
  }
}

__global__ void k_concat_bias(const float* __restrict__ bq, const float* __restrict__ bk,
                              const float* __restrict__ bv, float* __restrict__ out) {
  int i = blockIdx.x * blockDim.x + threadIdx.x;
  if (i < 1024) out[i] = bq[i];
  else if (i < 2048) out[i] = bk[i - 1024];
  else if (i < 3072) out[i] = bv[i - 2048];
}

// ---------------- GEMM (A row-major [M][K], BT row-major [N][K], both bf16) ----------------
// EPI=0: QKV epilogue. q is PRE-SCALED by 1/sqrt(128) so attention needs no scale.

template <int EPI>
__global__ __launch_bounds__(256) void k_gemm_bt(
    const unsigned short* __restrict__ A, const unsigned short* __restrict__ BT,
    const float* __restrict__ bias, int K,
    unsigned short* __restrict__ oq, unsigned short* __restrict__ ok,
    unsigned short* __restrict__ ovt, float* __restrict__ of) {
  __shared__ __align__(16) unsigned short Al[128][48];
  __shared__ __align__(16) unsigned short Bl[128][48];
  const int tid = threadIdx.x;
  const int lane = tid & 63, wave = tid >> 6;
  const int wm = wave >> 1, wn = wave & 1;
  const int lr = lane & 15, lg = lane >> 4;
  const int m0 = blockIdx.y * 128, n0 = blockIdx.x * 128;
  f32x4 acc[4][4] = {};
  const int srow = tid >> 2, skc = (tid & 3) * 8;

  for (int k0 = 0; k0 < K; k0 += 32) {
    __syncthreads();
#pragma unroll
    for (int p = 0; p < 2; p++) {
      int row = srow + (p << 6);
      *reinterpret_cast<ushort8*>(&Al[row][skc]) =
          *reinterpret_cast<const ushort8*>(A + (size_t)(m0 + row) * K + k0 + skc);
      *reinterpret_cast<ushort8*>(&Bl[row][skc]) =
          *reinterpret_cast<const ushort8*>(BT + (size_t)(n0 + row) * K + k0 + skc);
    }
    __syncthreads();
    bf16x8 af[4], bfr[4];
#pragma unroll
    for (int i = 0; i < 4; i++)
      af[i] = *reinterpret_cast<const bf16x8*>(&Al[wm * 64 + i * 16 + lr][lg * 8]);
#pragma unroll
    for (int i = 0; i < 4; i++)
      bfr[i] = *reinterpret_cast<const bf16x8*>(&Bl[wn * 64 + i * 16 + lr][lg * 8]);
#pragma unroll
    for (int i = 0; i < 4; i++)
#pragma unroll
      for (int j = 0; j < 4; j++)
        acc[i][j] = mfma16(af[i], bfr[j], acc[i][j]);
  }

#pragma unroll
  for (int i = 0; i < 4; i++) {
#pragma unroll
    for (int j = 0; j < 4; j++) {
      const int n = n0 + wn * 64 + j * 16 + lr;
      const float bv = bias[n];
      const int mb = m0 + wm * 64 + i * 16 + lg * 4;
      if (EPI == 0) {
        const int region = n >> 10;
        const int h = (n & 1023) >> 7, d = n & 127;
        if (region == 2) {
          ushort4v pk;
#pragma unroll
          for (int r = 0; r < 4; r++) pk[r] = f2bf(acc[i][j][r] + bv);
          const int bb = mb >> 11, s = mb & 2047;
          *reinterpret_cast<ushort4v*>(ovt + ((size_t)((bb * NH_ + h) * VD_ + d)) * SS_ + s) = pk;
        } else {
          unsigned short* dst = (region == 0) ? oq : ok;
          const float qs = (region == 0) ? 0.08838834764831845f : 1.0f;  // pre-scale q
#pragma unroll
          for (int r = 0; r < 4; r++) {
            const int m = mb + r;
            const int bb = m >> 11, s = m & 2047;
            dst[((size_t)((bb * NH_ + h) * SS_ + s)) * QK_ + d] = f2bf((acc[i][j][r] + bv) * qs);
          }
        }
      } else {
#pragma unroll
        for (int r = 0; r < 4; r++) {
          const int m = mb + r;
          of[(size_t)m * DIM_ + n] = acc[i][j][r] + bv;
        }
      }
    }
  }
}

// ---------------- flash attention: 2-wave blocks, split-K, S^T structure ----------------
// grid (NH, 128, B): linear%8 == h -> each XCD owns ONE head (both batches);
// K/V hot set (2 MB) stays L2-resident per XCD. Same-CU blocks are
// {yt, yt+32, yt+64, yt+96} x {b}; rt = b ? 127-yt : yt makes per-CU k-tile
// sums ~constant (antisymmetric pairing) -> no tail imbalance.
// Block 128 thr = 2 waves; wave0 k-tiles [0,h0), wave1 [h0,nkt); exact merge.
// pe loaded nontemporal (stream-once; don't evict K/V from L2), directly as
// the QK^T MFMA C-operand (q pre-scaled by 1/sqrt(128)).

__global__ __launch_bounds__(128, 4) void k_attn(
    const unsigned short* __restrict__ q, const unsigned short* __restrict__ k,
    const unsigned short* __restrict__ vt, const float* __restrict__ pe,
    unsigned short* __restrict__ att) {
  __shared__ __align__(16) unsigned short P[2][16][72];   // 4.5 KB, wave-private
  __shared__ __align__(16) unsigned short Xo[16][132];    // 4.1 KB, wave1 -> wave0
  __shared__ float Xml[16][2];

  const int h = blockIdx.x, b = blockIdx.z;
  const int yt = blockIdx.y;
  const int rt = b ? (127 - yt) : yt;   // per-CU work balance (see header)

  const int lane = threadIdx.x & 63, wave = threadIdx.x >> 6;
  const int lr = lane & 15, lg = lane >> 4;
  const int myq = rt * 16 + lr;  // this lane's q-row (S^T/O^T layout)

  const unsigned short* qp = q + (size_t)(b * NH_ + h) * SS_ * QK_;
  const unsigned short* kp = k + (size_t)(b * NH_ + h) * SS_ * QK_;
  const unsigned short* vp = vt + (size_t)(b * NH_ + h) * VD_ * SS_;
  const float* pep = pe + (size_t)h * SS_ * SS_ + (size_t)myq * SS_;

  // Q fragments (pre-scaled), reused every iteration
  bf16x8 qf[4];
#pragma unroll
  for (int c = 0; c < 4; c++)
    qf[c] = *reinterpret_cast<const bf16x8*>(qp + (size_t)myq * QK_ + c * 32 + lg * 8);

  f32x4 o[8] = {};  // O^T frags: d = sub*16+lg*4+r, q = myq (unnormalized)
  float m = -1e30f, l = 0.f;

  const int nkt = (rt >> 2) + 1;
  const int h0 = (nkt + 1) >> 1;
  const int kt_lo = wave ? h0 : 0;
  const int kt_hi = wave ? nkt : h0;

  for (int kt = kt_lo; kt < kt_hi; kt++) {
    const int kbase = kt * 64;

    // V^T fragments for kk=0, issued first
    bf16x8 vf[8];
#pragma unroll
    for (int sub = 0; sub < 8; sub++)
      vf[sub] = *reinterpret_cast<const bf16x8*>(
          vp + (size_t)(sub * 16 + lr) * SS_ + kbase + lg * 8);

    // S^T = K*Q^T + pe : C-operand initialized from pe (nontemporal float4)
    f32x4 sc[4];
#pragma unroll
    for (int ck = 0; ck < 4; ck++)
      sc[ck] = __builtin_nontemporal_load(
          reinterpret_cast<const f32x4*>(pep + kbase + ck * 16 + lg * 4));
#pragma unroll
    for (int ck = 0; ck < 4; ck++) {
#pragma unroll
      for (int c = 0; c < 4; c++) {
        const bf16x8 kf = *reinterpret_cast<const bf16x8*>(
            kp + (size_t)(kbase + ck * 16 + lr) * QK_ + c * 32 + lg * 8);
        sc[ck] = mfma16(kf, qf[c], sc[ck]);
      }
    }

    // causal mask (only the last tile of this q-row range touches the diagonal)
    const bool diag = (kt == nkt - 1);
    float tm = -1e30f;
#pragma unroll
    for (int ck = 0; ck < 4; ck++) {
#pragma unroll
      for (int r = 0; r < 4; r++) {
        float v = sc[ck][r];
        if (diag && (kbase + ck * 16 + lg * 4 + r) > myq) v = -1e30f;
        sc[ck][r] = v;
        tm = fmaxf(tm, v);
      }
    }
    tm = fmaxf(tm, __shfl_xor(tm, 16));
    tm = fmaxf(tm, __shfl_xor(tm, 32));

    const float mnew = fmaxf(m, tm);
    const float ps = __expf(m - mnew);
    m = mnew;
    float rsum = 0.f;
#pragma unroll
    for (int ck = 0; ck < 4; ck++)
#pragma unroll
      for (int r = 0; r < 4; r++) {
        const float p = __expf(sc[ck][r] - mnew);
        sc[ck][r] = p;
        rsum += p;
      }
    rsum += __shfl_xor(rsum, 16);
    rsum += __shfl_xor(rsum, 32);
    l = l * ps + rsum;
#pragma unroll
    for (int sub = 0; sub < 8; sub++)
#pragma unroll
      for (int r = 0; r < 4; r++) o[sub][r] *= ps;

    // P^T -> wave-private LDS
#pragma unroll
    for (int ck = 0; ck < 4; ck++) {
      ushort4v pk;
#pragma unroll
      for (int r = 0; r < 4; r++) pk[r] = f2bf(sc[ck][r]);
      *reinterpret_cast<ushort4v*>(&P[wave][lr][ck * 16 + lg * 4]) = pk;
    }

    // PV kk=0
    {
      const bf16x8 pf = *reinterpret_cast<const bf16x8*>(&P[wave][lr][lg * 8]);
#pragma unroll
      for (int sub = 0; sub < 8; sub++)
        o[sub] = mfma16(vf[sub], pf, o[sub]);
    }
    // V^T fragments kk=1 (reuse regs), PV kk=1
#pragma unroll
    for (int sub = 0; sub < 8; sub++)
      vf[sub] = *reinterpret_cast<const bf16x8*>(
          vp + (size_t)(sub * 16 + lr) * SS_ + kbase + 32 + lg * 8);
    {
      const bf16x8 pf = *reinterpret_cast<const bf16x8*>(&P[wave][lr][32 + lg * 8]);
#pragma unroll
      for (int sub = 0; sub < 8; sub++)
        o[sub] = mfma16(vf[sub], pf, o[sub]);
    }
  }

  // wave1: publish normalized partial (o/l, m, l)
  if (wave) {
    const float inv = (l > 0.f) ? 1.0f / l : 0.f;
#pragma unroll
    for (int sub = 0; sub < 8; sub++) {
      ushort4v pk;
#pragma unroll
      for (int r = 0; r < 4; r++) pk[r] = f2bf(o[sub][r] * inv);
      *reinterpret_cast<ushort4v*>(&Xo[lr][sub * 16 + lg * 4]) = pk;
    }
    if (lg == 0) { Xml[lr][0] = m; Xml[lr][1] = l; }
  }
  __syncthreads();
  // wave0: merge and write
  if (!wave) {
    const float m1 = Xml[lr][0], l1 = Xml[lr][1];
    const float ms = fmaxf(m, m1);
    const float w0 = __expf(m - ms);         // applies to unnormalized o
    const float c0 = w0 * l;
    const float c1 = __expf(m1 - ms) * l1;
    const float invT = 1.0f / (c0 + c1);
    unsigned short* ob = att + (size_t)(b * SS_ + myq) * (NH_ * VD_) + h * VD_;
#pragma unroll
    for (int sub = 0; sub < 8; sub++) {
      const ushort4v o1 = *reinterpret_cast<const ushort4v*>(&Xo[lr][sub * 16 + lg * 4]);
      ushort4v pk;
#pragma unroll
      for (int r = 0; r < 4; r++) {
        union { unsigned int u; float f; } cv; cv.u = ((unsigned int)o1[r]) << 16;
        pk[r] = f2bf((w0 * o[sub][r] + c1 * cv.f) * invT);
      }
      *reinterpret_cast<ushort4v*>(ob + sub * 16 + lg * 4) = pk;
    }
  }
}

// ---------------- launcher ----------------

extern "C" void kernel_launch(void* const* d_in, const int* in_sizes, int n_in,
                              void* d_out, int out_size, void* d_ws, size_t ws_size,
                              hipStream_t stream) {
  const float* x    = (const float*)d_in[0];
  const float* pe   = (const float*)d_in[3];
  const float* wq_w = (const float*)d_in[4];
  const float* wq_b = (const float*)d_in[5];
  const float* wk_w = (const float*)d_in[6];
  const float* wk_b = (const float*)d_in[7];
  const float* wv_w = (const float*)d_in[8];
  const float* wv_b = (const float*)d_in[9];
  const float* wo_w = (const float*)d_in[10];
  const float* wo_b = (const float*)d_in[11];
  float* out = (float*)d_out;

  char* ws = (char*)d_ws;
  unsigned short* x_bf   = (unsigned short*)(ws);                 // 4 MB
  unsigned short* wqkv_t = (unsigned short*)(ws + 4194304);       // 3 MB
  unsigned short* wo_t   = (unsigned short*)(ws + 7340032);       // 1 MB
  float*          qkv_b  = (float*)(ws + 8388608);                // 12 KB
  unsigned short* qb     = (unsigned short*)(ws + 8400896);       // 8 MB
  unsigned short* kb     = (unsigned short*)(ws + 16789504);      // 8 MB
  unsigned short* vtb    = (unsigned short*)(ws + 25178112);      // 8 MB
  unsigned short* attb   = (unsigned short*)(ws + 33566720);      // 8 MB

  k_convert_x<<<2048, 256, 0, stream>>>(x, x_bf, (4096 * 512) / 4);
  {
    dim3 gt(16, 8);  // C=1024, R=512
    k_transpose_cvt<<<gt, 256, 0, stream>>>(wq_w, wqkv_t, 512, 1024);
    k_transpose_cvt<<<gt, 256, 0, stream>>>(wk_w, wqkv_t + 1024 * 512, 512, 1024);
    k_transpose_cvt<<<gt, 256, 0, stream>>>(wv_w, wqkv_t + 2048 * 512, 512, 1024);
    dim3 gt2(8, 16);  // C=512, R=1024
    k_transpose_cvt<<<gt2, 256, 0, stream>>>(wo_w, wo_t, 1024, 512);
  }
  k_concat_bias<<<12, 256, 0, stream>>>(wq_b, wk_b, wv_b, qkv_b);

  dim3 g1(24, 32);
  k_gemm_bt<0><<<g1, 256, 0, stream>>>(x_bf, wqkv_t, qkv_b, 512, qb, kb, vtb, nullptr);

  dim3 g2(NH_, 128, BB_);  // x=head -> XCD = head (L2 K/V locality)
  k_attn<<<g2, 128, 0, stream>>>(qb, kb, vtb, pe, attb);

  dim3 g3(4, 32);
  k_gemm_bt<1><<<g3, 256, 0, stream>>>(attb, wo_t, wo_b, 1024, nullptr, nullptr, nullptr, out);
}

// Round 8
// 195.747 us; speedup vs baseline: 1.7135x; 1.1896x over previous
//
#include <hip/hip_runtime.h>
#include <hip/hip_bf16.h>
#include <stdint.h>

#define BB_ 2
#define SS_ 2048
#define DIM_ 512
#define NH_ 8
#define QK_ 128
#define VD_ 128

typedef __attribute__((ext_vector_type(8))) short bf16x8;
typedef __attribute__((ext_vector_type(4))) float f32x4;
typedef __attribute__((ext_vector_type(8))) unsigned short ushort8;
typedef __attribute__((ext_vector_type(4))) unsigned short ushort4v;

__device__ __forceinline__ unsigned short f2bf(float f) {
  union { float f; unsigned int u; } v; v.f = f;
  unsigned int r = v.u + 0x7FFFu + ((v.u >> 16) & 1u);  // RNE
  return (unsigned short)(r >> 16);
}

__device__ __forceinline__ f32x4 mfma16(bf16x8 a, bf16x8 b, f32x4 c) {
  return __builtin_amdgcn_mfma_f32_16x16x32_bf16(a, b, c, 0, 0, 0);
}

// ---------------- convert / transpose kernels ----------------

__global__ void k_convert_x(const float* __restrict__ x, unsigned short* __restrict__ xb, int n4) {
  int i = blockIdx.x * blockDim.x + threadIdx.x;
  if (i < n4) {
    float4 v = reinterpret_cast<const float4*>(x)[i];
    ushort4v o;
    o[0] = f2bf(v.x); o[1] = f2bf(v.y); o[2] = f2bf(v.z); o[3] = f2bf(v.w);
    reinterpret_cast<ushort4v*>(xb)[i] = o;
  }
}

// src [R][C] fp32 -> dst [C][R] bf16 ; grid (C/64, R/64), block 256
__global__ void k_transpose_cvt(const float* __restrict__ src, unsigned short* __restrict__ dst,
                                int R, int C) {
  __shared__ float t[64][65];
  const int c0 = blockIdx.x * 64, r0 = blockIdx.y * 64;
  const int tid = threadIdx.x;
  const int rr = tid >> 4, cc4 = (tid & 15) * 4;
#pragma unroll
  for (int p = 0; p < 4; p++) {
    float4 v = *reinterpret_cast<const float4*>(src + (size_t)(r0 + rr + p * 16) * C + c0 + cc4);
    t[rr + p * 16][cc4 + 0] = v.x; t[rr + p * 16][cc4 + 1] = v.y;
    t[rr + p * 16][cc4 + 2] = v.z; t[rr + p * 16][cc4 + 3] = v.w;
  }
  __syncthreads();
  const int cl = tid >> 2, rb = (tid & 3) * 16;
#pragma unroll
  for (int g = 0; g < 2; g++) {
    ushort8 o;
#pragma unroll
    for (int j = 0; j < 8; j++) o[j] = f2bf(t[rb + g * 8 + j][cl]);
    *reinterpret_cast<ushort8*>(dst + (size_t)(c0 + cl) * R + r0 + rb + g * 8) = o;
  }
}

__global__ void k_concat_bias(const float* __restrict__ bq, const float* __restrict__ bk,
                              const float* __restrict__ bv, float* __restrict__ out) {
  int i = blockIdx.x * blockDim.x + threadIdx.x;
  if (i < 1024) out[i] = bq[i];
  else if (i < 2048) out[i] = bk[i - 1024];
  else if (i < 3072) out[i] = bv[i - 2048];
}

// ---------------- GEMM (A row-major [M][K], BT row-major [N][K], both bf16) ----------------
// EPI=0: QKV epilogue writing PRE-SWIZZLED MFMA-fragment layouts (per (b,h)):
//   Qf/Kf: [s/16][c=d/32][lane=lg*16+lr][e=d%8]   lane: lg=(d%32)/8, lr=s%16
//   Vf:    [s/32][d/16][lane=sg*16+dr][e=s%8]     sg=(s%32)/8, dr=d%16
// so attention loads are base + lane*16B (fully coalesced, 8 lines/inst).
// q pre-scaled by 1/sqrt(128).

template <int EPI>
__global__ __launch_bounds__(256) void k_gemm_bt(
    const unsigned short* __restrict__ A, const unsigned short* __restrict__ BT,
    const float* __restrict__ bias, int K,
    unsigned short* __restrict__ oq, unsigned short* __restrict__ ok,
    unsigned short* __restrict__ ovt, float* __restrict__ of) {
  __shared__ __align__(16) unsigned short Al[128][48];
  __shared__ __align__(16) unsigned short Bl[128][48];
  const int tid = threadIdx.x;
  const int lane = tid & 63, wave = tid >> 6;
  const int wm = wave >> 1, wn = wave & 1;
  const int lr = lane & 15, lg = lane >> 4;
  const int m0 = blockIdx.y * 128, n0 = blockIdx.x * 128;
  f32x4 acc[4][4] = {};
  const int srow = tid >> 2, skc = (tid & 3) * 8;

  for (int k0 = 0; k0 < K; k0 += 32) {
    __syncthreads();
#pragma unroll
    for (int p = 0; p < 2; p++) {
      int row = srow + (p << 6);
      *reinterpret_cast<ushort8*>(&Al[row][skc]) =
          *reinterpret_cast<const ushort8*>(A + (size_t)(m0 + row) * K + k0 + skc);
      *reinterpret_cast<ushort8*>(&Bl[row][skc]) =
          *reinterpret_cast<const ushort8*>(BT + (size_t)(n0 + row) * K + k0 + skc);
    }
    __syncthreads();
    bf16x8 af[4], bfr[4];
#pragma unroll
    for (int i = 0; i < 4; i++)
      af[i] = *reinterpret_cast<const bf16x8*>(&Al[wm * 64 + i * 16 + lr][lg * 8]);
#pragma unroll
    for (int i = 0; i < 4; i++)
      bfr[i] = *reinterpret_cast<const bf16x8*>(&Bl[wn * 64 + i * 16 + lr][lg * 8]);
#pragma unroll
    for (int i = 0; i < 4; i++)
#pragma unroll
      for (int j = 0; j < 4; j++)
        acc[i][j] = mfma16(af[i], bfr[j], acc[i][j]);
  }

#pragma unroll
  for (int i = 0; i < 4; i++) {
#pragma unroll
    for (int j = 0; j < 4; j++) {
      const int n = n0 + wn * 64 + j * 16 + lr;
      const float bv = bias[n];
      const int mb = m0 + wm * 64 + i * 16 + lg * 4;
      if (EPI == 0) {
        const int region = n >> 10;
        const int h = (n & 1023) >> 7, d = n & 127;
        const int bb = mb >> 11, s0 = mb & 2047;
        const size_t hb = (size_t)(bb * NH_ + h) << 18;  // 2048*128 per (b,h)
        if (region == 2) {
          ushort4v pk;
#pragma unroll
          for (int r = 0; r < 4; r++) pk[r] = f2bf(acc[i][j][r] + bv);
          const int s32 = s0 >> 5, sg = (s0 >> 3) & 3, e0 = s0 & 7;
          const size_t off = hb + (size_t)(((s32 * 8 + (d >> 4)) * 4 + sg) * 128 + (d & 15) * 8 + e0);
          *reinterpret_cast<ushort4v*>(ovt + off) = pk;
        } else {
          unsigned short* dst = ((region == 0) ? oq : ok) + hb;
          const float qs = (region == 0) ? 0.08838834764831845f : 1.0f;  // pre-scale q
          const int rt_ = s0 >> 4, c_ = d >> 5, lg_ = (d >> 3) & 3, e_ = d & 7;
          const int lrb = s0 & 15;
#pragma unroll
          for (int r = 0; r < 4; r++)
            dst[(size_t)(((rt_ * 4 + c_) * 64 + lg_ * 16 + lrb + r) * 8 + e_)] =
                f2bf((acc[i][j][r] + bv) * qs);
        }
      } else {
#pragma unroll
        for (int r = 0; r < 4; r++) {
          const int m = mb + r;
          of[(size_t)m * DIM_ + n] = acc[i][j][r] + bv;
        }
      }
    }
  }
}

// ---------------- flash attention: coalesced fragment loads, split-K ----------------
// grid (NH, 128, B): XCD = head (K/V L2-resident). Block 128 = 2 waves; wave0
// k-tiles [0,h0), wave1 [h0,nkt); exact online-softmax merge at the end.
// Q/K/V read from pre-swizzled fragment buffers: every load = base + lane*16B.
// pe: 4 coalesced row-segment loads issued early, LDS-transposed (XOR-swizzled,
// wave-private, no barrier) into S^T fragment order while QK^T MFMAs run.

__global__ __launch_bounds__(128, 4) void k_attn(
    const unsigned short* __restrict__ q, const unsigned short* __restrict__ k,
    const unsigned short* __restrict__ vt, const float* __restrict__ pe,
    unsigned short* __restrict__ att) {
  __shared__ __align__(16) unsigned short P[2][16][72];   // 4.5 KB, wave-private
  __shared__ __align__(16) float PEl[2][16][64];          // 8 KB, wave-private
  __shared__ __align__(16) unsigned short Xo[16][132];    // 4.1 KB, wave1 -> wave0
  __shared__ float Xml[16][2];

  const int h = blockIdx.x, b = blockIdx.z;
  const int yt = blockIdx.y;
  const int rt = b ? (127 - yt) : yt;   // per-CU work balance

  const int lane = threadIdx.x & 63, wave = threadIdx.x >> 6;
  const int lr = lane & 15, lg = lane >> 4;
  const int myq = rt * 16 + lr;  // this lane's q-row (S^T/O^T layout)

  const size_t hb = (size_t)(b * NH_ + h) << 18;
  const unsigned short* qfp = q + hb;
  const unsigned short* kfp = k + hb;
  const unsigned short* vfp = vt + hb;
  const float* pet = pe + (size_t)h * SS_ * SS_ + (size_t)(rt * 16) * SS_;
  char* PEw = (char*)&PEl[wave][0][0];

  // Q fragments (pre-scaled), coalesced: (rt*4+c)*512 + lane*8
  bf16x8 qf[4];
#pragma unroll
  for (int c = 0; c < 4; c++)
    qf[c] = *reinterpret_cast<const bf16x8*>(qfp + ((size_t)(rt * 4 + c) << 9) + (lane << 3));

  f32x4 o[8] = {};  // O^T frags: d = sub*16+lg*4+r, q = myq (unnormalized)
  float m = -1e30f, l = 0.f;

  const int nkt = (rt >> 2) + 1;
  const int h0 = (nkt + 1) >> 1;
  const int kt_lo = wave ? h0 : 0;
  const int kt_hi = wave ? nkt : h0;

  const int prow = lane >> 4;          // staging row-in-chunk
  const int pcb = (lane & 15) << 4;    // staging col-byte

  for (int kt = kt_lo; kt < kt_hi; kt++) {
    const int kbase = kt * 64;

    // 1. pe row-segments: coalesced 16-lane x 16B per row, issued EARLY
    f32x4 pg[4];
#pragma unroll
    for (int w = 0; w < 4; w++) {
      const int row = w * 4 + prow;
      pg[w] = *reinterpret_cast<const f32x4*>(
          (const char*)(pet + (size_t)row * SS_ + kbase) + pcb);
    }

    // 2. V^T fragments kk=0, coalesced
    bf16x8 vf[8];
#pragma unroll
    for (int sub = 0; sub < 8; sub++)
      vf[sub] = *reinterpret_cast<const bf16x8*>(
          vfp + ((size_t)((kt * 2) * 8 + sub) << 9) + (lane << 3));

    // 3. S^T = K*Q^T (C=0), K fragments coalesced
    f32x4 sc[4] = {};
#pragma unroll
    for (int ck = 0; ck < 4; ck++) {
#pragma unroll
      for (int c = 0; c < 4; c++) {
        const bf16x8 kf = *reinterpret_cast<const bf16x8*>(
            kfp + ((size_t)((kt * 4 + ck) * 4 + c) << 9) + (lane << 3));
        sc[ck] = mfma16(kf, qf[c], sc[ck]);
      }
    }

    // 4. pe -> LDS (XOR-swizzled write; the vmcnt wait lands here, after MFMAs)
#pragma unroll
    for (int w = 0; w < 4; w++) {
      const int row = w * 4 + prow;
      *reinterpret_cast<f32x4*>(PEw + row * 256 + (pcb ^ ((row & 7) << 4))) = pg[w];
    }
    // swizzled conflict-free read into S^T fragment order
    f32x4 pe4[4];
#pragma unroll
    for (int ck = 0; ck < 4; ck++)
      pe4[ck] = *reinterpret_cast<const f32x4*>(
          PEw + lr * 256 + ((ck * 64 + lg * 16) ^ ((lr & 7) << 4)));

    // 5. add pe + causal mask + online softmax (in-lane)
    const bool diag = (kt == nkt - 1);
    float tm = -1e30f;
#pragma unroll
    for (int ck = 0; ck < 4; ck++) {
#pragma unroll
      for (int r = 0; r < 4; r++) {
        float v = sc[ck][r] + pe4[ck][r];
        if (diag && (kbase + ck * 16 + lg * 4 + r) > myq) v = -1e30f;
        sc[ck][r] = v;
        tm = fmaxf(tm, v);
      }
    }
    tm = fmaxf(tm, __shfl_xor(tm, 16));
    tm = fmaxf(tm, __shfl_xor(tm, 32));

    const float mnew = fmaxf(m, tm);
    const float ps = __expf(m - mnew);
    m = mnew;
    float rsum = 0.f;
#pragma unroll
    for (int ck = 0; ck < 4; ck++)
#pragma unroll
      for (int r = 0; r < 4; r++) {
        const float p = __expf(sc[ck][r] - mnew);
        sc[ck][r] = p;
        rsum += p;
      }
    rsum += __shfl_xor(rsum, 16);
    rsum += __shfl_xor(rsum, 32);
    l = l * ps + rsum;
#pragma unroll
    for (int sub = 0; sub < 8; sub++)
#pragma unroll
      for (int r = 0; r < 4; r++) o[sub][r] *= ps;

    // P^T -> wave-private LDS
#pragma unroll
    for (int ck = 0; ck < 4; ck++) {
      ushort4v pk;
#pragma unroll
      for (int r = 0; r < 4; r++) pk[r] = f2bf(sc[ck][r]);
      *reinterpret_cast<ushort4v*>(&P[wave][lr][ck * 16 + lg * 4]) = pk;
    }

    // PV kk=0
    {
      const bf16x8 pf = *reinterpret_cast<const bf16x8*>(&P[wave][lr][lg * 8]);
#pragma unroll
      for (int sub = 0; sub < 8; sub++)
        o[sub] = mfma16(vf[sub], pf, o[sub]);
    }
    // V^T fragments kk=1 (coalesced, reuse regs), PV kk=1
#pragma unroll
    for (int sub = 0; sub < 8; sub++)
      vf[sub] = *reinterpret_cast<const bf16x8*>(
          vfp + ((size_t)((kt * 2 + 1) * 8 + sub) << 9) + (lane << 3));
    {
      const bf16x8 pf = *reinterpret_cast<const bf16x8*>(&P[wave][lr][32 + lg * 8]);
#pragma unroll
      for (int sub = 0; sub < 8; sub++)
        o[sub] = mfma16(vf[sub], pf, o[sub]);
    }
  }

  // wave1: publish normalized partial (o/l, m, l)
  if (wave) {
    const float inv = (l > 0.f) ? 1.0f / l : 0.f;
#pragma unroll
    for (int sub = 0; sub < 8; sub++) {
      ushort4v pk;
#pragma unroll
      for (int r = 0; r < 4; r++) pk[r] = f2bf(o[sub][r] * inv);
      *reinterpret_cast<ushort4v*>(&Xo[lr][sub * 16 + lg * 4]) = pk;
    }
    if (lg == 0) { Xml[lr][0] = m; Xml[lr][1] = l; }
  }
  __syncthreads();
  // wave0: merge and write
  if (!wave) {
    const float m1 = Xml[lr][0], l1 = Xml[lr][1];
    const float ms = fmaxf(m, m1);
    const float w0 = __expf(m - ms);         // applies to unnormalized o
    const float c0 = w0 * l;
    const float c1 = __expf(m1 - ms) * l1;
    const float invT = 1.0f / (c0 + c1);
    unsigned short* ob = att + (size_t)(b * SS_ + myq) * (NH_ * VD_) + h * VD_;
#pragma unroll
    for (int sub = 0; sub < 8; sub++) {
      const ushort4v o1 = *reinterpret_cast<const ushort4v*>(&Xo[lr][sub * 16 + lg * 4]);
      ushort4v pk;
#pragma unroll
      for (int r = 0; r < 4; r++) {
        union { unsigned int u; float f; } cv; cv.u = ((unsigned int)o1[r]) << 16;
        pk[r] = f2bf((w0 * o[sub][r] + c1 * cv.f) * invT);
      }
      *reinterpret_cast<ushort4v*>(ob + sub * 16 + lg * 4) = pk;
    }
  }
}

// ---------------- launcher ----------------

extern "C" void kernel_launch(void* const* d_in, const int* in_sizes, int n_in,
                              void* d_out, int out_size, void* d_ws, size_t ws_size,
                              hipStream_t stream) {
  const float* x    = (const float*)d_in[0];
  const float* pe   = (const float*)d_in[3];
  const float* wq_w = (const float*)d_in[4];
  const float* wq_b = (const float*)d_in[5];
  const float* wk_w = (const float*)d_in[6];
  const float* wk_b = (const float*)d_in[7];
  const float* wv_w = (const float*)d_in[8];
  const float* wv_b = (const float*)d_in[9];
  const float* wo_w = (const float*)d_in[10];
  const float* wo_b = (const float*)d_in[11];
  float* out = (float*)d_out;

  char* ws = (char*)d_ws;
  unsigned short* x_bf   = (unsigned short*)(ws);                 // 4 MB
  unsigned short* wqkv_t = (unsigned short*)(ws + 4194304);       // 3 MB
  unsigned short* wo_t   = (unsigned short*)(ws + 7340032);       // 1 MB
  float*          qkv_b  = (float*)(ws + 8388608);                // 12 KB
  unsigned short* qb     = (unsigned short*)(ws + 8400896);       // 8 MB (Qf)
  unsigned short* kb     = (unsigned short*)(ws + 16789504);      // 8 MB (Kf)
  unsigned short* vtb    = (unsigned short*)(ws + 25178112);      // 8 MB (Vf)
  unsigned short* attb   = (unsigned short*)(ws + 33566720);      // 8 MB

  k_convert_x<<<2048, 256, 0, stream>>>(x, x_bf, (4096 * 512) / 4);
  {
    dim3 gt(16, 8);  // C=1024, R=512
    k_transpose_cvt<<<gt, 256, 0, stream>>>(wq_w, wqkv_t, 512, 1024);
    k_transpose_cvt<<<gt, 256, 0, stream>>>(wk_w, wqkv_t + 1024 * 512, 512, 1024);
    k_transpose_cvt<<<gt, 256, 0, stream>>>(wv_w, wqkv_t + 2048 * 512, 512, 1024);
    dim3 gt2(8, 16);  // C=512, R=1024
    k_transpose_cvt<<<gt2, 256, 0, stream>>>(wo_w, wo_t, 1024, 512);
  }
  k_concat_bias<<<12, 256, 0, stream>>>(wq_b, wk_b, wv_b, qkv_b);

  dim3 g1(24, 32);
  k_gemm_bt<0><<<g1, 256, 0, stream>>>(x_bf, wqkv_t, qkv_b, 512, qb, kb, vtb, nullptr);

  dim3 g2(NH_, 128, BB_);  // x=head -> XCD = head (L2 K/V locality)
  k_attn<<<g2, 128, 0, stream>>>(qb, kb, vtb, pe, attb);

  dim3 g3(4, 32);
  k_gemm_bt<1><<<g3, 256, 0, stream>>>(attb, wo_t, wo_b, 1024, nullptr, nullptr, nullptr, out);
}

// Round 9
// 146.169 us; speedup vs baseline: 2.2947x; 1.3392x over previous
//
#include <hip/hip_runtime.h>
#include <hip/hip_bf16.h>
#include <stdint.h>

#define BB_ 2
#define SS_ 2048
#define DIM_ 512
#define NH_ 8
#define QK_ 128
#define VD_ 128

typedef __attribute__((ext_vector_type(8))) short bf16x8;
typedef __attribute__((ext_vector_type(4))) float f32x4;
typedef __attribute__((ext_vector_type(8))) unsigned short ushort8;
typedef __attribute__((ext_vector_type(4))) unsigned short ushort4v;

__device__ __forceinline__ unsigned short f2bf(float f) {
  union { float f; unsigned int u; } v; v.f = f;
  unsigned int r = v.u + 0x7FFFu + ((v.u >> 16) & 1u);  // RNE
  return (unsigned short)(r >> 16);
}

__device__ __forceinline__ f32x4 mfma16(bf16x8 a, bf16x8 b, f32x4 c) {
  return __builtin_amdgcn_mfma_f32_16x16x32_bf16(a, b, c, 0, 0, 0);
}

// ---------------- convert / transpose kernels ----------------

__global__ void k_convert_x(const float* __restrict__ x, unsigned short* __restrict__ xb, int n4) {
  int i = blockIdx.x * blockDim.x + threadIdx.x;
  if (i < n4) {
    float4 v = reinterpret_cast<const float4*>(x)[i];
    ushort4v o;
    o[0] = f2bf(v.x); o[1] = f2bf(v.y); o[2] = f2bf(v.z); o[3] = f2bf(v.w);
    reinterpret_cast<ushort4v*>(xb)[i] = o;
  }
}

// src [R][C] fp32 -> dst [C][R] bf16 ; grid (C/64, R/64), block 256
__global__ void k_transpose_cvt(const float* __restrict__ src, unsigned short* __restrict__ dst,
                                int R, int C) {
  __shared__ float t[64][65];
  const int c0 = blockIdx.x * 64, r0 = blockIdx.y * 64;
  const int tid = threadIdx.x;
  const int rr = tid >> 4, cc4 = (tid & 15) * 4;
#pragma unroll
  for (int p = 0; p < 4; p++) {
    float4 v = *reinterpret_cast<const float4*>(src + (size_t)(r0 + rr + p * 16) * C + c0 + cc4);
    t[rr + p * 16][cc4 + 0] = v.x; t[rr + p * 16][cc4 + 1] = v.y;
    t[rr + p * 16][cc4 + 2] = v.z; t[rr + p * 16][cc4 + 3] = v.w;
  }
  __syncthreads();
  const int cl = tid >> 2, rb = (tid & 3) * 16;
#pragma unroll
  for (int g = 0; g < 2; g++) {
    ushort8 o;
#pragma unroll
    for (int j = 0; j < 8; j++) o[j] = f2bf(t[rb + g * 8 + j][cl]);
    *reinterpret_cast<ushort8*>(dst + (size_t)(c0 + cl) * R + r0 + rb + g * 8) = o;
  }
}

__global__ void k_concat_bias(const float* __restrict__ bq, const float* __restrict__ bk,
                              const float* __restrict__ bv, float* __restrict__ out) {
  int i = blockIdx.x * blockDim.x + threadIdx.x;
  if (i < 1024) out[i] = bq[i];
  else if (i < 2048) out[i] = bk[i - 1024];
  else if (i < 3072) out[i] = bv[i - 2048];
}

// ---------------- GEMM (A row-major [M][K], BT row-major [N][K], both bf16) ----------------
// EPI=0: QKV epilogue writing PRE-SWIZZLED MFMA-fragment layouts (per (b,h)):
//   Qf/Kf: [s/16][c=d/32][lane=lg*16+lr][e=d%8]   lane: lg=(d%32)/8, lr=s%16
//   Vf:    [s/32][d/16][lane=sg*16+dr][e=s%8]     sg=(s%32)/8, dr=d%16
// so attention loads are base + lane*16B (fully coalesced). q pre-scaled by 1/sqrt(128).

template <int EPI>
__global__ __launch_bounds__(256) void k_gemm_bt(
    const unsigned short* __restrict__ A, const unsigned short* __restrict__ BT,
    const float* __restrict__ bias, int K,
    unsigned short* __restrict__ oq, unsigned short* __restrict__ ok,
    unsigned short* __restrict__ ovt, float* __restrict__ of) {
  __shared__ __align__(16) unsigned short Al[128][48];
  __shared__ __align__(16) unsigned short Bl[128][48];
  const int tid = threadIdx.x;
  const int lane = tid & 63, wave = tid >> 6;
  const int wm = wave >> 1, wn = wave & 1;
  const int lr = lane & 15, lg = lane >> 4;
  const int m0 = blockIdx.y * 128, n0 = blockIdx.x * 128;
  f32x4 acc[4][4] = {};
  const int srow = tid >> 2, skc = (tid & 3) * 8;

  for (int k0 = 0; k0 < K; k0 += 32) {
    __syncthreads();
#pragma unroll
    for (int p = 0; p < 2; p++) {
      int row = srow + (p << 6);
      *reinterpret_cast<ushort8*>(&Al[row][skc]) =
          *reinterpret_cast<const ushort8*>(A + (size_t)(m0 + row) * K + k0 + skc);
      *reinterpret_cast<ushort8*>(&Bl[row][skc]) =
          *reinterpret_cast<const ushort8*>(BT + (size_t)(n0 + row) * K + k0 + skc);
    }
    __syncthreads();
    bf16x8 af[4], bfr[4];
#pragma unroll
    for (int i = 0; i < 4; i++)
      af[i] = *reinterpret_cast<const bf16x8*>(&Al[wm * 64 + i * 16 + lr][lg * 8]);
#pragma unroll
    for (int i = 0; i < 4; i++)
      bfr[i] = *reinterpret_cast<const bf16x8*>(&Bl[wn * 64 + i * 16 + lr][lg * 8]);
#pragma unroll
    for (int i = 0; i < 4; i++)
#pragma unroll
      for (int j = 0; j < 4; j++)
        acc[i][j] = mfma16(af[i], bfr[j], acc[i][j]);
  }

#pragma unroll
  for (int i = 0; i < 4; i++) {
#pragma unroll
    for (int j = 0; j < 4; j++) {
      const int n = n0 + wn * 64 + j * 16 + lr;
      const float bv = bias[n];
      const int mb = m0 + wm * 64 + i * 16 + lg * 4;
      if (EPI == 0) {
        const int region = n >> 10;
        const int h = (n & 1023) >> 7, d = n & 127;
        const int bb = mb >> 11, s0 = mb & 2047;
        const size_t hb = (size_t)(bb * NH_ + h) << 18;  // 2048*128 per (b,h)
        if (region == 2) {
          ushort4v pk;
#pragma unroll
          for (int r = 0; r < 4; r++) pk[r] = f2bf(acc[i][j][r] + bv);
          const int s32 = s0 >> 5, sg = (s0 >> 3) & 3, e0 = s0 & 7;
          const size_t off = hb + (size_t)(((s32 * 8 + (d >> 4)) * 4 + sg) * 128 + (d & 15) * 8 + e0);
          *reinterpret_cast<ushort4v*>(ovt + off) = pk;
        } else {
          unsigned short* dst = ((region == 0) ? oq : ok) + hb;
          const float qs = (region == 0) ? 0.08838834764831845f : 1.0f;  // pre-scale q
          const int rt_ = s0 >> 4, c_ = d >> 5, lg_ = (d >> 3) & 3, e_ = d & 7;
          const int lrb = s0 & 15;
#pragma unroll
          for (int r = 0; r < 4; r++)
            dst[(size_t)(((rt_ * 4 + c_) * 64 + lg_ * 16 + lrb + r) * 8 + e_)] =
                f2bf((acc[i][j][r] + bv) * qs);
        }
      } else {
#pragma unroll
        for (int r = 0; r < 4; r++) {
          const int m = mb + r;
          of[(size_t)m * DIM_ + n] = acc[i][j][r] + bv;
        }
      }
    }
  }
}

// ---------------- flash attention: QBLK=32 per wave (2 q-tiles), split-K ----------------
// grid (NH, 64, B) = 1024 blocks (exactly 4/CU); XCD = head (K/V + pe L2 locality).
// Block 128 = 2 waves, each wave owns the SAME 32 q-rows; wave0 k-tiles [0,h0),
// wave1 [h0,nkt); exact online-softmax merge at the end.
// Each kf/vf load feeds TWO MFMAs (2 q-tiles) -> 64 MFMA per 40 VMEM ops/iter,
// and the two tiles' softmax chains run in parallel (ILP).
// launch_bounds(128,2): 256-reg cap, ~190 needed -> NO SPILL (R4/R8 lesson).
// pe loaded nontemporal directly as the QK^T C-operand (q pre-scaled).

__global__ __launch_bounds__(128, 2) void k_attn(
    const unsigned short* __restrict__ q, const unsigned short* __restrict__ k,
    const unsigned short* __restrict__ vt, const float* __restrict__ pe,
    unsigned short* __restrict__ att) {
  __shared__ __align__(16) unsigned short P[2][2][16][72];  // 9 KB, wave-private
  __shared__ __align__(16) unsigned short Xo[32][132];      // 8.4 KB, wave1 -> wave0
  __shared__ float Xml[32][2];

  const int h = blockIdx.x, b = blockIdx.z;
  const int yt = blockIdx.y;            // 0..63
  const int rt = b ? (63 - yt) : yt;    // q-tile32; per-CU k-tile sum ~const

  const int lane = threadIdx.x & 63, wave = threadIdx.x >> 6;
  const int lr = lane & 15, lg = lane >> 4;
  const int myq0 = rt * 32 + lr;        // tile t's q-row = myq0 + t*16

  const size_t hb = (size_t)(b * NH_ + h) << 18;
  const unsigned short* qfp = q + hb;
  const unsigned short* kfp = k + hb;
  const unsigned short* vfp = vt + hb;
  const float* pep = pe + (size_t)h * SS_ * SS_ + (size_t)myq0 * SS_;  // +t*16*SS_

  // Q fragments (pre-scaled), coalesced: ((rt*2+t)*4+c)*512 + lane*8
  bf16x8 qf[2][4];
#pragma unroll
  for (int t = 0; t < 2; t++)
#pragma unroll
    for (int c = 0; c < 4; c++)
      qf[t][c] = *reinterpret_cast<const bf16x8*>(
          qfp + ((size_t)((rt * 2 + t) * 4 + c) << 9) + (lane << 3));

  f32x4 o[2][8] = {};  // O^T frags per tile: d = sub*16+lg*4+r (unnormalized)
  float m[2] = {-1e30f, -1e30f}, l[2] = {0.f, 0.f};

  const int nkt = (rt >> 1) + 1;        // k-tiles of 64 covering the diagonal
  const int h0 = (nkt + 1) >> 1;
  const int kt_lo = wave ? h0 : 0;
  const int kt_hi = wave ? nkt : h0;

  for (int kt = kt_lo; kt < kt_hi; kt++) {
    const int kbase = kt * 64;

    // V^T fragments kk=0 (shared by both tiles), coalesced
    bf16x8 vf[8];
#pragma unroll
    for (int sub = 0; sub < 8; sub++)
      vf[sub] = *reinterpret_cast<const bf16x8*>(
          vfp + ((size_t)((kt * 2) * 8 + sub) << 9) + (lane << 3));

    // S^T = K*Q^T + pe : C init from pe (nontemporal), both tiles
    f32x4 sc[2][4];
#pragma unroll
    for (int t = 0; t < 2; t++)
#pragma unroll
      for (int ck = 0; ck < 4; ck++)
        sc[t][ck] = __builtin_nontemporal_load(reinterpret_cast<const f32x4*>(
            pep + (size_t)(t * 16) * SS_ + kbase + ck * 16 + lg * 4));

    // QK^T: each kf feeds both tiles
#pragma unroll
    for (int ck = 0; ck < 4; ck++) {
#pragma unroll
      for (int c = 0; c < 4; c++) {
        const bf16x8 kf = *reinterpret_cast<const bf16x8*>(
            kfp + ((size_t)((kt * 4 + ck) * 4 + c) << 9) + (lane << 3));
        sc[0][ck] = mfma16(kf, qf[0][c], sc[0][ck]);
        sc[1][ck] = mfma16(kf, qf[1][c], sc[1][ck]);
      }
    }

    // causal mask + online softmax, two independent chains
    const bool diag = (kt == nkt - 1);
    float ps[2], rsum[2];
#pragma unroll
    for (int t = 0; t < 2; t++) {
      const int mq = myq0 + t * 16;
      float tm = -1e30f;
#pragma unroll
      for (int ck = 0; ck < 4; ck++) {
#pragma unroll
        for (int r = 0; r < 4; r++) {
          float v = sc[t][ck][r];
          if (diag && (kbase + ck * 16 + lg * 4 + r) > mq) v = -1e30f;
          sc[t][ck][r] = v;
          tm = fmaxf(tm, v);
        }
      }
      tm = fmaxf(tm, __shfl_xor(tm, 16));
      tm = fmaxf(tm, __shfl_xor(tm, 32));
      const float mnew = fmaxf(m[t], tm);
      ps[t] = __expf(m[t] - mnew);
      m[t] = mnew;
      float rs = 0.f;
#pragma unroll
      for (int ck = 0; ck < 4; ck++)
#pragma unroll
        for (int r = 0; r < 4; r++) {
          const float p = __expf(sc[t][ck][r] - mnew);
          sc[t][ck][r] = p;
          rs += p;
        }
      rsum[t] = rs;
    }
#pragma unroll
    for (int t = 0; t < 2; t++) {
      float rs = rsum[t];
      rs += __shfl_xor(rs, 16);
      rs += __shfl_xor(rs, 32);
      l[t] = l[t] * ps[t] + rs;
#pragma unroll
      for (int sub = 0; sub < 8; sub++)
#pragma unroll
        for (int r = 0; r < 4; r++) o[t][sub][r] *= ps[t];
      // P^T -> wave-private LDS
#pragma unroll
      for (int ck = 0; ck < 4; ck++) {
        ushort4v pk;
#pragma unroll
        for (int r = 0; r < 4; r++) pk[r] = f2bf(sc[t][ck][r]);
        *reinterpret_cast<ushort4v*>(&P[wave][t][lr][ck * 16 + lg * 4]) = pk;
      }
    }

    // PV kk=0 (vf shared by both tiles)
#pragma unroll
    for (int t = 0; t < 2; t++) {
      const bf16x8 pf = *reinterpret_cast<const bf16x8*>(&P[wave][t][lr][lg * 8]);
#pragma unroll
      for (int sub = 0; sub < 8; sub++)
        o[t][sub] = mfma16(vf[sub], pf, o[t][sub]);
    }
    // V^T kk=1 (reuse regs), PV kk=1
#pragma unroll
    for (int sub = 0; sub < 8; sub++)
      vf[sub] = *reinterpret_cast<const bf16x8*>(
          vfp + ((size_t)((kt * 2 + 1) * 8 + sub) << 9) + (lane << 3));
#pragma unroll
    for (int t = 0; t < 2; t++) {
      const bf16x8 pf = *reinterpret_cast<const bf16x8*>(&P[wave][t][lr][32 + lg * 8]);
#pragma unroll
      for (int sub = 0; sub < 8; sub++)
        o[t][sub] = mfma16(vf[sub], pf, o[t][sub]);
    }
  }

  // wave1: publish normalized partials (o/l, m, l), rows t*16+lr
  if (wave) {
#pragma unroll
    for (int t = 0; t < 2; t++) {
      const float inv = (l[t] > 0.f) ? 1.0f / l[t] : 0.f;
#pragma unroll
      for (int sub = 0; sub < 8; sub++) {
        ushort4v pk;
#pragma unroll
        for (int r = 0; r < 4; r++) pk[r] = f2bf(o[t][sub][r] * inv);
        *reinterpret_cast<ushort4v*>(&Xo[t * 16 + lr][sub * 16 + lg * 4]) = pk;
      }
      if (lg == 0) { Xml[t * 16 + lr][0] = m[t]; Xml[t * 16 + lr][1] = l[t]; }
    }
  }
  __syncthreads();
  // wave0: merge and write
  if (!wave) {
#pragma unroll
    for (int t = 0; t < 2; t++) {
      const float m1 = Xml[t * 16 + lr][0], l1 = Xml[t * 16 + lr][1];
      const float ms = fmaxf(m[t], m1);
      const float w0 = __expf(m[t] - ms);   // applies to unnormalized o
      const float c0 = w0 * l[t];
      const float c1 = __expf(m1 - ms) * l1;
      const float invT = 1.0f / (c0 + c1);
      unsigned short* ob = att + (size_t)(b * SS_ + myq0 + t * 16) * (NH_ * VD_) + h * VD_;
#pragma unroll
      for (int sub = 0; sub < 8; sub++) {
        const ushort4v o1 = *reinterpret_cast<const ushort4v*>(&Xo[t * 16 + lr][sub * 16 + lg * 4]);
        ushort4v pk;
#pragma unroll
        for (int r = 0; r < 4; r++) {
          union { unsigned int u; float f; } cv; cv.u = ((unsigned int)o1[r]) << 16;
          pk[r] = f2bf((w0 * o[t][sub][r] + c1 * cv.f) * invT);
        }
        *reinterpret_cast<ushort4v*>(ob + sub * 16 + lg * 4) = pk;
      }
    }
  }
}

// ---------------- launcher ----------------

extern "C" void kernel_launch(void* const* d_in, const int* in_sizes, int n_in,
                              void* d_out, int out_size, void* d_ws, size_t ws_size,
                              hipStream_t stream) {
  const float* x    = (const float*)d_in[0];
  const float* pe   = (const float*)d_in[3];
  const float* wq_w = (const float*)d_in[4];
  const float* wq_b = (const float*)d_in[5];
  const float* wk_w = (const float*)d_in[6];
  const float* wk_b = (const float*)d_in[7];
  const float* wv_w = (const float*)d_in[8];
  const float* wv_b = (const float*)d_in[9];
  const float* wo_w = (const float*)d_in[10];
  const float* wo_b = (const float*)d_in[11];
  float* out = (float*)d_out;

  char* ws = (char*)d_ws;
  unsigned short* x_bf   = (unsigned short*)(ws);                 // 4 MB
  unsigned short* wqkv_t = (unsigned short*)(ws + 4194304);       // 3 MB
  unsigned short* wo_t   = (unsigned short*)(ws + 7340032);       // 1 MB
  float*          qkv_b  = (float*)(ws + 8388608);                // 12 KB
  unsigned short* qb     = (unsigned short*)(ws + 8400896);       // 8 MB (Qf)
  unsigned short* kb     = (unsigned short*)(ws + 16789504);      // 8 MB (Kf)
  unsigned short* vtb    = (unsigned short*)(ws + 25178112);      // 8 MB (Vf)
  unsigned short* attb   = (unsigned short*)(ws + 33566720);      // 8 MB

  k_convert_x<<<2048, 256, 0, stream>>>(x, x_bf, (4096 * 512) / 4);
  {
    dim3 gt(16, 8);  // C=1024, R=512
    k_transpose_cvt<<<gt, 256, 0, stream>>>(wq_w, wqkv_t, 512, 1024);
    k_transpose_cvt<<<gt, 256, 0, stream>>>(wk_w, wqkv_t + 1024 * 512, 512, 1024);
    k_transpose_cvt<<<gt, 256, 0, stream>>>(wv_w, wqkv_t + 2048 * 512, 512, 1024);
    dim3 gt2(8, 16);  // C=512, R=1024
    k_transpose_cvt<<<gt2, 256, 0, stream>>>(wo_w, wo_t, 1024, 512);
  }
  k_concat_bias<<<12, 256, 0, stream>>>(wq_b, wk_b, wv_b, qkv_b);

  dim3 g1(24, 32);
  k_gemm_bt<0><<<g1, 256, 0, stream>>>(x_bf, wqkv_t, qkv_b, 512, qb, kb, vtb, nullptr);

  dim3 g2(NH_, 64, BB_);  // x=head -> XCD = head (L2 K/V + pe locality)
  k_attn<<<g2, 128, 0, stream>>>(qb, kb, vtb, pe, attb);

  dim3 g3(4, 32);
  k_gemm_bt<1><<<g3, 256, 0, stream>>>(attb, wo_t, wo_b, 1024, nullptr, nullptr, nullptr, out);
}

// Round 10
// 133.964 us; speedup vs baseline: 2.5038x; 1.0911x over previous
//
#include <hip/hip_runtime.h>
#include <hip/hip_bf16.h>
#include <stdint.h>

#define BB_ 2
#define SS_ 2048
#define DIM_ 512
#define NH_ 8
#define QK_ 128
#define VD_ 128

typedef __attribute__((ext_vector_type(8))) short bf16x8;
typedef __attribute__((ext_vector_type(4))) float f32x4;
typedef __attribute__((ext_vector_type(8))) unsigned short ushort8;
typedef __attribute__((ext_vector_type(4))) unsigned short ushort4v;

__device__ __forceinline__ unsigned short f2bf(float f) {
  union { float f; unsigned int u; } v; v.f = f;
  unsigned int r = v.u + 0x7FFFu + ((v.u >> 16) & 1u);  // RNE
  return (unsigned short)(r >> 16);
}

__device__ __forceinline__ f32x4 mfma16(bf16x8 a, bf16x8 b, f32x4 c) {
  return __builtin_amdgcn_mfma_f32_16x16x32_bf16(a, b, c, 0, 0, 0);
}

// ---------------- convert / transpose kernels ----------------

__global__ void k_convert_x(const float* __restrict__ x, unsigned short* __restrict__ xb, int n4) {
  int i = blockIdx.x * blockDim.x + threadIdx.x;
  if (i < n4) {
    float4 v = reinterpret_cast<const float4*>(x)[i];
    ushort4v o;
    o[0] = f2bf(v.x); o[1] = f2bf(v.y); o[2] = f2bf(v.z); o[3] = f2bf(v.w);
    reinterpret_cast<ushort4v*>(xb)[i] = o;
  }
}

// src [R][C] fp32 -> dst [C][R] bf16 ; grid (C/64, R/64), block 256
__global__ void k_transpose_cvt(const float* __restrict__ src, unsigned short* __restrict__ dst,
                                int R, int C) {
  __shared__ float t[64][65];
  const int c0 = blockIdx.x * 64, r0 = blockIdx.y * 64;
  const int tid = threadIdx.x;
  const int rr = tid >> 4, cc4 = (tid & 15) * 4;
#pragma unroll
  for (int p = 0; p < 4; p++) {
    float4 v = *reinterpret_cast<const float4*>(src + (size_t)(r0 + rr + p * 16) * C + c0 + cc4);
    t[rr + p * 16][cc4 + 0] = v.x; t[rr + p * 16][cc4 + 1] = v.y;
    t[rr + p * 16][cc4 + 2] = v.z; t[rr + p * 16][cc4 + 3] = v.w;
  }
  __syncthreads();
  const int cl = tid >> 2, rb = (tid & 3) * 16;
#pragma unroll
  for (int g = 0; g < 2; g++) {
    ushort8 o;
#pragma unroll
    for (int j = 0; j < 8; j++) o[j] = f2bf(t[rb + g * 8 + j][cl]);
    *reinterpret_cast<ushort8*>(dst + (size_t)(c0 + cl) * R + r0 + rb + g * 8) = o;
  }
}

__global__ void k_concat_bias(const float* __restrict__ bq, const float* __restrict__ bk,
                              const float* __restrict__ bv, float* __restrict__ out) {
  int i = blockIdx.x * blockDim.x + threadIdx.x;
  if (i < 1024) out[i] = bq[i];
  else if (i < 2048) out[i] = bk[i - 1024];
  else if (i < 3072) out[i] = bv[i - 2048];
}

// ---------------- GEMM (A row-major [M][K], BT row-major [N][K], both bf16) ----------------
// Staging via global_load_lds width-16 (m97 recipe). EPI=0 writes pre-swizzled
// MFMA-fragment layouts for attention (see R8/R9 notes); q pre-scaled by 1/sqrt(128).

template <int EPI>
__global__ __launch_bounds__(256) void k_gemm_bt(
    const unsigned short* __restrict__ A, const unsigned short* __restrict__ BT,
    const float* __restrict__ bias, int K,
    unsigned short* __restrict__ oq, unsigned short* __restrict__ ok,
    unsigned short* __restrict__ ovt, float* __restrict__ of) {
  __shared__ __align__(16) unsigned short Al[128][32];
  __shared__ __align__(16) unsigned short Bl[128][32];
  const int tid = threadIdx.x;
  const int lane = tid & 63, wave = tid >> 6;
  const int wm = wave >> 1, wn = wave & 1;
  const int lr = lane & 15, lg = lane >> 4;
  const int m0 = blockIdx.y * 128, n0 = blockIdx.x * 128;
  f32x4 acc[4][4] = {};
  const int srow = lane >> 2, scol = (lane & 3) * 8;  // staging: 16 rows x 64B per wave-inst

  for (int k0 = 0; k0 < K; k0 += 32) {
    __syncthreads();
    {
      const unsigned short* ga = A + (size_t)(m0 + wave * 16 + srow) * K + k0 + scol;
      __builtin_amdgcn_global_load_lds((const unsigned int*)ga,
                                       (unsigned int*)&Al[wave * 16][0], 16, 0, 0);
      __builtin_amdgcn_global_load_lds((const unsigned int*)(ga + (size_t)64 * K),
                                       (unsigned int*)&Al[wave * 16 + 64][0], 16, 0, 0);
      const unsigned short* gb = BT + (size_t)(n0 + wave * 16 + srow) * K + k0 + scol;
      __builtin_amdgcn_global_load_lds((const unsigned int*)gb,
                                       (unsigned int*)&Bl[wave * 16][0], 16, 0, 0);
      __builtin_amdgcn_global_load_lds((const unsigned int*)(gb + (size_t)64 * K),
                                       (unsigned int*)&Bl[wave * 16 + 64][0], 16, 0, 0);
    }
    __syncthreads();
    bf16x8 af[4], bfr[4];
#pragma unroll
    for (int i = 0; i < 4; i++)
      af[i] = *reinterpret_cast<const bf16x8*>(&Al[wm * 64 + i * 16 + lr][lg * 8]);
#pragma unroll
    for (int i = 0; i < 4; i++)
      bfr[i] = *reinterpret_cast<const bf16x8*>(&Bl[wn * 64 + i * 16 + lr][lg * 8]);
#pragma unroll
    for (int i = 0; i < 4; i++)
#pragma unroll
      for (int j = 0; j < 4; j++)
        acc[i][j] = mfma16(af[i], bfr[j], acc[i][j]);
  }

#pragma unroll
  for (int i = 0; i < 4; i++) {
#pragma unroll
    for (int j = 0; j < 4; j++) {
      const int n = n0 + wn * 64 + j * 16 + lr;
      const float bv = bias[n];
      const int mb = m0 + wm * 64 + i * 16 + lg * 4;
      if (EPI == 0) {
        const int region = n >> 10;
        const int h = (n & 1023) >> 7, d = n & 127;
        const int bb = mb >> 11, s0 = mb & 2047;
        const size_t hb = (size_t)(bb * NH_ + h) << 18;  // 2048*128 per (b,h)
        if (region == 2) {
          ushort4v pk;
#pragma unroll
          for (int r = 0; r < 4; r++) pk[r] = f2bf(acc[i][j][r] + bv);
          const int s32 = s0 >> 5, sg = (s0 >> 3) & 3, e0 = s0 & 7;
          const size_t off = hb + (size_t)(((s32 * 8 + (d >> 4)) * 4 + sg) * 128 + (d & 15) * 8 + e0);
          *reinterpret_cast<ushort4v*>(ovt + off) = pk;
        } else {
          unsigned short* dst = ((region == 0) ? oq : ok) + hb;
          const float qs = (region == 0) ? 0.08838834764831845f : 1.0f;  // pre-scale q
          const int rt_ = s0 >> 4, c_ = d >> 5, lg_ = (d >> 3) & 3, e_ = d & 7;
          const int lrb = s0 & 15;
#pragma unroll
          for (int r = 0; r < 4; r++)
            dst[(size_t)(((rt_ * 4 + c_) * 64 + lg_ * 16 + lrb + r) * 8 + e_)] =
                f2bf((acc[i][j][r] + bv) * qs);
        }
      } else {
#pragma unroll
        for (int r = 0; r < 4; r++) {
          const int m = mb + r;
          of[(size_t)m * DIM_ + n] = acc[i][j][r] + bv;
        }
      }
    }
  }
}

// ---------------- flash attention: QBLK=32/wave, split-K, pe LDS-prefetch ----------------
// grid (NH, 64, B) = 1024 blocks; XCD = head (K/V L2-resident). Block 128 = 2
// waves, same 32 q-rows; wave0 k-tiles [0,h0), wave1 [h0,nkt); exact merge.
// pe (read-once, HBM-latency) is prefetched ONE K-TILE AHEAD into wave-private
// double-buffered LDS via global_load_lds (zero VGPR cost), with both-sides
// XOR swizzle (inverse-swizzled global source + swizzled ds_read) so the
// row-strided fragment read is conflict-free. Explicit vmcnt(0)+sched_barrier
// before the pe read: at that point only the prefetch is outstanding.

__global__ __launch_bounds__(128, 2) void k_attn(
    const unsigned short* __restrict__ q, const unsigned short* __restrict__ k,
    const unsigned short* __restrict__ vt, const float* __restrict__ pe,
    unsigned short* __restrict__ att) {
  __shared__ __align__(16) unsigned short P[2][2][16][72];  // 9 KB, wave-private
  __shared__ __align__(16) float PEL[2][2][32][64];         // 32 KB, wave-private dbuf
  __shared__ __align__(16) unsigned short Xo[32][132];      // 8.4 KB, wave1 -> wave0
  __shared__ float Xml[32][2];

  const int h = blockIdx.x, b = blockIdx.z;
  const int yt = blockIdx.y;            // 0..63
  const int rt = b ? (63 - yt) : yt;    // q-tile32; per-CU k-tile sum ~const

  const int lane = threadIdx.x & 63, wave = threadIdx.x >> 6;
  const int lr = lane & 15, lg = lane >> 4;
  const int myq0 = rt * 32 + lr;        // tile t's q-row = myq0 + t*16

  const size_t hb = (size_t)(b * NH_ + h) << 18;
  const unsigned short* qfp = q + hb;
  const unsigned short* kfp = k + hb;
  const unsigned short* vfp = vt + hb;
  const float* peb = pe + (size_t)h * SS_ * SS_ + (size_t)(rt * 32) * SS_;  // block-tile base

  // pe staging: 8 x global_load_lds(16B); rows 0..31, row = g*4 + lane/16,
  // source col pre-swizzled so linear LDS write lands XOR-swizzled.
  const int prg = lane >> 4;            // 0..3
  const int pcb = (lane & 15) << 4;     // 0..240 byte col
  auto pe_stage = [&](int kt, int buf) {
    float* base = &PEL[wave][buf][0][0];
#pragma unroll
    for (int g = 0; g < 8; g++) {
      const int row = g * 4 + prg;
      const char* src = (const char*)(peb + (size_t)row * SS_ + kt * 64) + (pcb ^ ((row & 7) << 4));
      __builtin_amdgcn_global_load_lds((const unsigned int*)src,
                                       (unsigned int*)(base + g * 256), 16, 0, 0);
    }
  };

  // Q fragments (pre-scaled), coalesced
  bf16x8 qf[2][4];
#pragma unroll
  for (int t = 0; t < 2; t++)
#pragma unroll
    for (int c = 0; c < 4; c++)
      qf[t][c] = *reinterpret_cast<const bf16x8*>(
          qfp + ((size_t)((rt * 2 + t) * 4 + c) << 9) + (lane << 3));

  f32x4 o[2][8] = {};  // O^T frags per tile (unnormalized)
  float m[2] = {-1e30f, -1e30f}, l[2] = {0.f, 0.f};

  const int nkt = (rt >> 1) + 1;
  const int h0 = (nkt + 1) >> 1;
  const int kt_lo = wave ? h0 : 0;
  const int kt_hi = wave ? nkt : h0;

  pe_stage(kt_lo, 0);
  int pbuf = 0;

  for (int kt = kt_lo; kt < kt_hi; kt++) {
    const int kbase = kt * 64;

    // pe fragment read from LDS (swizzled); only the prefetch is outstanding here
    asm volatile("s_waitcnt vmcnt(0)" ::: "memory");
    __builtin_amdgcn_sched_barrier(0);
    const char* pebase = (const char*)&PEL[wave][pbuf][0][0];
    f32x4 sc[2][4];
#pragma unroll
    for (int t = 0; t < 2; t++)
#pragma unroll
      for (int ck = 0; ck < 4; ck++)
        sc[t][ck] = *reinterpret_cast<const f32x4*>(
            pebase + (t * 16 + lr) * 256 + ((ck * 64 + lg * 16) ^ ((lr & 7) << 4)));

    // prefetch next tile's pe into the other buffer (hides under QK+softmax+PV)
    if (kt + 1 < kt_hi) pe_stage(kt + 1, pbuf ^ 1);
    pbuf ^= 1;

    // V^T fragments kk=0 (shared by both tiles), coalesced
    bf16x8 vf[8];
#pragma unroll
    for (int sub = 0; sub < 8; sub++)
      vf[sub] = *reinterpret_cast<const bf16x8*>(
          vfp + ((size_t)((kt * 2) * 8 + sub) << 9) + (lane << 3));

    // QK^T: each kf feeds both tiles; C-init = pe
    __builtin_amdgcn_s_setprio(1);
#pragma unroll
    for (int ck = 0; ck < 4; ck++) {
#pragma unroll
      for (int c = 0; c < 4; c++) {
        const bf16x8 kf = *reinterpret_cast<const bf16x8*>(
            kfp + ((size_t)((kt * 4 + ck) * 4 + c) << 9) + (lane << 3));
        sc[0][ck] = mfma16(kf, qf[0][c], sc[0][ck]);
        sc[1][ck] = mfma16(kf, qf[1][c], sc[1][ck]);
      }
    }
    __builtin_amdgcn_s_setprio(0);

    // causal mask + online softmax, two independent chains
    const bool diag = (kt == nkt - 1);
    float ps[2], rsum[2];
#pragma unroll
    for (int t = 0; t < 2; t++) {
      const int mq = myq0 + t * 16;
      float tm = -1e30f;
#pragma unroll
      for (int ck = 0; ck < 4; ck++) {
#pragma unroll
        for (int r = 0; r < 4; r++) {
          float v = sc[t][ck][r];
          if (diag && (kbase + ck * 16 + lg * 4 + r) > mq) v = -1e30f;
          sc[t][ck][r] = v;
          tm = fmaxf(tm, v);
        }
      }
      tm = fmaxf(tm, __shfl_xor(tm, 16));
      tm = fmaxf(tm, __shfl_xor(tm, 32));
      const float mnew = fmaxf(m[t], tm);
      ps[t] = __expf(m[t] - mnew);
      m[t] = mnew;
      float rs = 0.f;
#pragma unroll
      for (int ck = 0; ck < 4; ck++)
#pragma unroll
        for (int r = 0; r < 4; r++) {
          const float p = __expf(sc[t][ck][r] - mnew);
          sc[t][ck][r] = p;
          rs += p;
        }
      rsum[t] = rs;
    }
#pragma unroll
    for (int t = 0; t < 2; t++) {
      float rs = rsum[t];
      rs += __shfl_xor(rs, 16);
      rs += __shfl_xor(rs, 32);
      l[t] = l[t] * ps[t] + rs;
#pragma unroll
      for (int sub = 0; sub < 8; sub++)
#pragma unroll
        for (int r = 0; r < 4; r++) o[t][sub][r] *= ps[t];
      // P^T -> wave-private LDS
#pragma unroll
      for (int ck = 0; ck < 4; ck++) {
        ushort4v pk;
#pragma unroll
        for (int r = 0; r < 4; r++) pk[r] = f2bf(sc[t][ck][r]);
        *reinterpret_cast<ushort4v*>(&P[wave][t][lr][ck * 16 + lg * 4]) = pk;
      }
    }

    // PV kk=0 (vf shared by both tiles)
    __builtin_amdgcn_s_setprio(1);
#pragma unroll
    for (int t = 0; t < 2; t++) {
      const bf16x8 pf = *reinterpret_cast<const bf16x8*>(&P[wave][t][lr][lg * 8]);
#pragma unroll
      for (int sub = 0; sub < 8; sub++)
        o[t][sub] = mfma16(vf[sub], pf, o[t][sub]);
    }
    __builtin_amdgcn_s_setprio(0);
    // V^T kk=1 (reuse regs), PV kk=1
#pragma unroll
    for (int sub = 0; sub < 8; sub++)
      vf[sub] = *reinterpret_cast<const bf16x8*>(
          vfp + ((size_t)((kt * 2 + 1) * 8 + sub) << 9) + (lane << 3));
    __builtin_amdgcn_s_setprio(1);
#pragma unroll
    for (int t = 0; t < 2; t++) {
      const bf16x8 pf = *reinterpret_cast<const bf16x8*>(&P[wave][t][lr][32 + lg * 8]);
#pragma unroll
      for (int sub = 0; sub < 8; sub++)
        o[t][sub] = mfma16(vf[sub], pf, o[t][sub]);
    }
    __builtin_amdgcn_s_setprio(0);
  }

  // wave1: publish normalized partials (o/l, m, l), rows t*16+lr
  if (wave) {
#pragma unroll
    for (int t = 0; t < 2; t++) {
      const float inv = (l[t] > 0.f) ? 1.0f / l[t] : 0.f;
#pragma unroll
      for (int sub = 0; sub < 8; sub++) {
        ushort4v pk;
#pragma unroll
        for (int r = 0; r < 4; r++) pk[r] = f2bf(o[t][sub][r] * inv);
        *reinterpret_cast<ushort4v*>(&Xo[t * 16 + lr][sub * 16 + lg * 4]) = pk;
      }
      if (lg == 0) { Xml[t * 16 + lr][0] = m[t]; Xml[t * 16 + lr][1] = l[t]; }
    }
  }
  __syncthreads();
  // wave0: merge and write
  if (!wave) {
#pragma unroll
    for (int t = 0; t < 2; t++) {
      const float m1 = Xml[t * 16 + lr][0], l1 = Xml[t * 16 + lr][1];
      const float ms = fmaxf(m[t], m1);
      const float w0 = __expf(m[t] - ms);   // applies to unnormalized o
      const float c0 = w0 * l[t];
      const float c1 = __expf(m1 - ms) * l1;
      const float invT = 1.0f / (c0 + c1);
      unsigned short* ob = att + (size_t)(b * SS_ + myq0 + t * 16) * (NH_ * VD_) + h * VD_;
#pragma unroll
      for (int sub = 0; sub < 8; sub++) {
        const ushort4v o1 = *reinterpret_cast<const ushort4v*>(&Xo[t * 16 + lr][sub * 16 + lg * 4]);
        ushort4v pk;
#pragma unroll
        for (int r = 0; r < 4; r++) {
          union { unsigned int u; float f; } cv; cv.u = ((unsigned int)o1[r]) << 16;
          pk[r] = f2bf((w0 * o[t][sub][r] + c1 * cv.f) * invT);
        }
        *reinterpret_cast<ushort4v*>(ob + sub * 16 + lg * 4) = pk;
      }
    }
  }
}

// ---------------- launcher ----------------

extern "C" void kernel_launch(void* const* d_in, const int* in_sizes, int n_in,
                              void* d_out, int out_size, void* d_ws, size_t ws_size,
                              hipStream_t stream) {
  const float* x    = (const float*)d_in[0];
  const float* pe   = (const float*)d_in[3];
  const float* wq_w = (const float*)d_in[4];
  const float* wq_b = (const float*)d_in[5];
  const float* wk_w = (const float*)d_in[6];
  const float* wk_b = (const float*)d_in[7];
  const float* wv_w = (const float*)d_in[8];
  const float* wv_b = (const float*)d_in[9];
  const float* wo_w = (const float*)d_in[10];
  const float* wo_b = (const float*)d_in[11];
  float* out = (float*)d_out;

  char* ws = (char*)d_ws;
  unsigned short* x_bf   = (unsigned short*)(ws);                 // 4 MB
  unsigned short* wqkv_t = (unsigned short*)(ws + 4194304);       // 3 MB
  unsigned short* wo_t   = (unsigned short*)(ws + 7340032);       // 1 MB
  float*          qkv_b  = (float*)(ws + 8388608);                // 12 KB
  unsigned short* qb     = (unsigned short*)(ws + 8400896);       // 8 MB (Qf)
  unsigned short* kb     = (unsigned short*)(ws + 16789504);      // 8 MB (Kf)
  unsigned short* vtb    = (unsigned short*)(ws + 25178112);      // 8 MB (Vf)
  unsigned short* attb   = (unsigned short*)(ws + 33566720);      // 8 MB

  k_convert_x<<<2048, 256, 0, stream>>>(x, x_bf, (4096 * 512) / 4);
  {
    dim3 gt(16, 8);  // C=1024, R=512
    k_transpose_cvt<<<gt, 256, 0, stream>>>(wq_w, wqkv_t, 512, 1024);
    k_transpose_cvt<<<gt, 256, 0, stream>>>(wk_w, wqkv_t + 1024 * 512, 512, 1024);
    k_transpose_cvt<<<gt, 256, 0, stream>>>(wv_w, wqkv_t + 2048 * 512, 512, 1024);
    dim3 gt2(8, 16);  // C=512, R=1024
    k_transpose_cvt<<<gt2, 256, 0, stream>>>(wo_w, wo_t, 1024, 512);
  }
  k_concat_bias<<<12, 256, 0, stream>>>(wq_b, wk_b, wv_b, qkv_b);

  dim3 g1(24, 32);
  k_gemm_bt<0><<<g1, 256, 0, stream>>>(x_bf, wqkv_t, qkv_b, 512, qb, kb, vtb, nullptr);

  dim3 g2(NH_, 64, BB_);  // x=head -> XCD = head (L2 K/V locality)
  k_attn<<<g2, 128, 0, stream>>>(qb, kb, vtb, pe, attb);

  dim3 g3(4, 32);
  k_gemm_bt<1><<<g3, 256, 0, stream>>>(attb, wo_t, wo_b, 1024, nullptr, nullptr, nullptr, out);
}

// Round 12
// 119.294 us; speedup vs baseline: 2.8117x; 1.1230x over previous
//
#include <hip/hip_runtime.h>
#include <hip/hip_bf16.h>
#include <stdint.h>

#define BB_ 2
#define SS_ 2048
#define DIM_ 512
#define NH_ 8
#define QK_ 128
#define VD_ 128

typedef __attribute__((ext_vector_type(8))) short bf16x8;
typedef __attribute__((ext_vector_type(4))) float f32x4;
typedef __attribute__((ext_vector_type(8))) unsigned short ushort8;
typedef __attribute__((ext_vector_type(4))) unsigned short ushort4v;

__device__ __forceinline__ unsigned short f2bf(float f) {
  union { float f; unsigned int u; } v; v.f = f;
  unsigned int r = v.u + 0x7FFFu + ((v.u >> 16) & 1u);  // RNE
  return (unsigned short)(r >> 16);
}

__device__ __forceinline__ float bf2f(unsigned short u) {
  union { unsigned int u; float f; } v; v.u = ((unsigned int)u) << 16;
  return v.f;
}

__device__ __forceinline__ f32x4 mfma16(bf16x8 a, bf16x8 b, f32x4 c) {
  return __builtin_amdgcn_mfma_f32_16x16x32_bf16(a, b, c, 0, 0, 0);
}

// ---------------- convert / transpose kernels ----------------

__global__ void k_convert_x(const float* __restrict__ x, unsigned short* __restrict__ xb, int n4) {
  int i = blockIdx.x * blockDim.x + threadIdx.x;
  if (i < n4) {
    float4 v = reinterpret_cast<const float4*>(x)[i];
    ushort4v o;
    o[0] = f2bf(v.x); o[1] = f2bf(v.y); o[2] = f2bf(v.z); o[3] = f2bf(v.w);
    reinterpret_cast<ushort4v*>(xb)[i] = o;
  }
}

// src [R][C] fp32 -> dst [C][R] bf16 ; grid (C/64, R/64), block 256
__global__ void k_transpose_cvt(const float* __restrict__ src, unsigned short* __restrict__ dst,
                                int R, int C) {
  __shared__ float t[64][65];
  const int c0 = blockIdx.x * 64, r0 = blockIdx.y * 64;
  const int tid = threadIdx.x;
  const int rr = tid >> 4, cc4 = (tid & 15) * 4;
#pragma unroll
  for (int p = 0; p < 4; p++) {
    float4 v = *reinterpret_cast<const float4*>(src + (size_t)(r0 + rr + p * 16) * C + c0 + cc4);
    t[rr + p * 16][cc4 + 0] = v.x; t[rr + p * 16][cc4 + 1] = v.y;
    t[rr + p * 16][cc4 + 2] = v.z; t[rr + p * 16][cc4 + 3] = v.w;
  }
  __syncthreads();
  const int cl = tid >> 2, rb = (tid & 3) * 16;
#pragma unroll
  for (int g = 0; g < 2; g++) {
    ushort8 o;
#pragma unroll
    for (int j = 0; j < 8; j++) o[j] = f2bf(t[rb + g * 8 + j][cl]);
    *reinterpret_cast<ushort8*>(dst + (size_t)(c0 + cl) * R + r0 + rb + g * 8) = o;
  }
}

__global__ void k_concat_bias(const float* __restrict__ bq, const float* __restrict__ bk,
                              const float* __restrict__ bv, float* __restrict__ out) {
  int i = blockIdx.x * blockDim.x + threadIdx.x;
  if (i < 1024) out[i] = bq[i];
  else if (i < 2048) out[i] = bk[i - 1024];
  else if (i < 3072) out[i] = bv[i - 2048];
}

// ---------------- GEMM (A row-major [M][K], BT row-major [N][K], both bf16) ----------------
// Staging via global_load_lds width-16. EPI=0 writes pre-swizzled MFMA-fragment
// layouts for attention; q pre-scaled by 1/sqrt(128).

template <int EPI>
__global__ __launch_bounds__(256) void k_gemm_bt(
    const unsigned short* __restrict__ A, const unsigned short* __restrict__ BT,
    const float* __restrict__ bias, int K,
    unsigned short* __restrict__ oq, unsigned short* __restrict__ ok,
    unsigned short* __restrict__ ovt, float* __restrict__ of) {
  __shared__ __align__(16) unsigned short Al[128][32];
  __shared__ __align__(16) unsigned short Bl[128][32];
  const int tid = threadIdx.x;
  const int lane = tid & 63, wave = tid >> 6;
  const int wm = wave >> 1, wn = wave & 1;
  const int lr = lane & 15, lg = lane >> 4;
  const int m0 = blockIdx.y * 128, n0 = blockIdx.x * 128;
  f32x4 acc[4][4] = {};
  const int srow = lane >> 2, scol = (lane & 3) * 8;

  for (int k0 = 0; k0 < K; k0 += 32) {
    __syncthreads();
    {
      const unsigned short* ga = A + (size_t)(m0 + wave * 16 + srow) * K + k0 + scol;
      __builtin_amdgcn_global_load_lds((const unsigned int*)ga,
                                       (unsigned int*)&Al[wave * 16][0], 16, 0, 0);
      __builtin_amdgcn_global_load_lds((const unsigned int*)(ga + (size_t)64 * K),
                                       (unsigned int*)&Al[wave * 16 + 64][0], 16, 0, 0);
      const unsigned short* gb = BT + (size_t)(n0 + wave * 16 + srow) * K + k0 + scol;
      __builtin_amdgcn_global_load_lds((const unsigned int*)gb,
                                       (unsigned int*)&Bl[wave * 16][0], 16, 0, 0);
      __builtin_amdgcn_global_load_lds((const unsigned int*)(gb + (size_t)64 * K),
                                       (unsigned int*)&Bl[wave * 16 + 64][0], 16, 0, 0);
    }
    __syncthreads();
    bf16x8 af[4], bfr[4];
#pragma unroll
    for (int i = 0; i < 4; i++)
      af[i] = *reinterpret_cast<const bf16x8*>(&Al[wm * 64 + i * 16 + lr][lg * 8]);
#pragma unroll
    for (int i = 0; i < 4; i++)
      bfr[i] = *reinterpret_cast<const bf16x8*>(&Bl[wn * 64 + i * 16 + lr][lg * 8]);
#pragma unroll
    for (int i = 0; i < 4; i++)
#pragma unroll
      for (int j = 0; j < 4; j++)
        acc[i][j] = mfma16(af[i], bfr[j], acc[i][j]);
  }

#pragma unroll
  for (int i = 0; i < 4; i++) {
#pragma unroll
    for (int j = 0; j < 4; j++) {
      const int n = n0 + wn * 64 + j * 16 + lr;
      const float bv = bias[n];
      const int mb = m0 + wm * 64 + i * 16 + lg * 4;
      if (EPI == 0) {
        const int region = n >> 10;
        const int h = (n & 1023) >> 7, d = n & 127;
        const int bb = mb >> 11, s0 = mb & 2047;
        const size_t hb = (size_t)(bb * NH_ + h) << 18;
        if (region == 2) {
          ushort4v pk;
#pragma unroll
          for (int r = 0; r < 4; r++) pk[r] = f2bf(acc[i][j][r] + bv);
          const int s32 = s0 >> 5, sg = (s0 >> 3) & 3, e0 = s0 & 7;
          const size_t off = hb + (size_t)(((s32 * 8 + (d >> 4)) * 4 + sg) * 128 + (d & 15) * 8 + e0);
          *reinterpret_cast<ushort4v*>(ovt + off) = pk;
        } else {
          unsigned short* dst = ((region == 0) ? oq : ok) + hb;
          const float qs = (region == 0) ? 0.08838834764831845f : 1.0f;
          const int rt_ = s0 >> 4, c_ = d >> 5, lg_ = (d >> 3) & 3, e_ = d & 7;
          const int lrb = s0 & 15;
#pragma unroll
          for (int r = 0; r < 4; r++)
            dst[(size_t)(((rt_ * 4 + c_) * 64 + lg_ * 16 + lrb + r) * 8 + e_)] =
                f2bf((acc[i][j][r] + bv) * qs);
        }
      } else {
#pragma unroll
        for (int r = 0; r < 4; r++) {
          const int m = mb + r;
          of[(size_t)m * DIM_ + n] = acc[i][j][r] + bv;
        }
      }
    }
  }
}

// ---------------- flash attention: uniform-work blocks, 4-way split-K ----------------
// grid (NH, 32, B) = 512 blocks x 4 waves = 2048 waves, ALL co-resident; every
// block does the SAME work: q-tile pair (p, 63-p) sequentially, each phase
// 4-way split-K across the 4 waves (per-block total = 33 k-tiles) -> no
// makespan tail. pe: b=0/b=1 blocks with same (h,p) read identical pe rows on
// the same XCD -> L2 reuse halves pe HBM traffic. pe loads go straight into
// the QK^T C-operand (q pre-scaled by 1/sqrt(128)).
// Merge: all 4 waves publish normalized partials (o/l, m, l) to LDS; each wave
// merges 8 rows x 128 cols = 16 elems/thread (R11 BUG: was 8/thread -> half
// the d-range unwritten).

__global__ __launch_bounds__(256, 2) void k_attn(
    const unsigned short* __restrict__ q, const unsigned short* __restrict__ k,
    const unsigned short* __restrict__ vt, const float* __restrict__ pe,
    unsigned short* __restrict__ att) {
  __shared__ __align__(16) unsigned short P[4][2][16][72];   // 18 KB, wave-private
  __shared__ __align__(16) unsigned short Xo[4][32][136];    // 34.8 KB partials
  __shared__ float Xml[4][32][2];                            // 1 KB

  const int h = blockIdx.x, p = blockIdx.y, b = blockIdx.z;
  const int lane = threadIdx.x & 63, wave = threadIdx.x >> 6;
  const int lr = lane & 15, lg = lane >> 4;

  const size_t hb = (size_t)(b * NH_ + h) << 18;
  const unsigned short* qfp = q + hb;
  const unsigned short* kfp = k + hb;
  const unsigned short* vfp = vt + hb;
  const float* peh = pe + (size_t)h * SS_ * SS_;

  for (int phase = 0; phase < 2; phase++) {
    const int rt = phase ? (63 - p) : p;     // q-tile32 index
    const int myq0 = rt * 32 + lr;           // tile t's q-row = myq0 + t*16
    const float* pep = peh + (size_t)myq0 * SS_;

    // Q fragments (pre-scaled), coalesced
    bf16x8 qf[2][4];
#pragma unroll
    for (int t = 0; t < 2; t++)
#pragma unroll
      for (int c = 0; c < 4; c++)
        qf[t][c] = *reinterpret_cast<const bf16x8*>(
            qfp + ((size_t)((rt * 2 + t) * 4 + c) << 9) + (lane << 3));

    f32x4 o[2][8] = {};
    float m[2] = {-1e30f, -1e30f}, l[2] = {0.f, 0.f};

    const int nkt = (rt >> 1) + 1;
    const int kt_lo = (nkt * wave) >> 2;
    const int kt_hi = (nkt * (wave + 1)) >> 2;

    for (int kt = kt_lo; kt < kt_hi; kt++) {
      const int kbase = kt * 64;

      // V^T fragments kk=0 (shared by both tiles), coalesced
      bf16x8 vf[8];
#pragma unroll
      for (int sub = 0; sub < 8; sub++)
        vf[sub] = *reinterpret_cast<const bf16x8*>(
            vfp + ((size_t)((kt * 2) * 8 + sub) << 9) + (lane << 3));

      // S^T = K*Q^T + pe : C init from pe (cached loads -> cross-b L2 reuse)
      f32x4 sc[2][4];
#pragma unroll
      for (int t = 0; t < 2; t++)
#pragma unroll
        for (int ck = 0; ck < 4; ck++)
          sc[t][ck] = *reinterpret_cast<const f32x4*>(
              pep + (size_t)(t * 16) * SS_ + kbase + ck * 16 + lg * 4);

      __builtin_amdgcn_s_setprio(1);
#pragma unroll
      for (int ck = 0; ck < 4; ck++) {
#pragma unroll
        for (int c = 0; c < 4; c++) {
          const bf16x8 kf = *reinterpret_cast<const bf16x8*>(
              kfp + ((size_t)((kt * 4 + ck) * 4 + c) << 9) + (lane << 3));
          sc[0][ck] = mfma16(kf, qf[0][c], sc[0][ck]);
          sc[1][ck] = mfma16(kf, qf[1][c], sc[1][ck]);
        }
      }
      __builtin_amdgcn_s_setprio(0);

      // causal mask + online softmax, two independent chains
      const bool diag = (kt == nkt - 1);
      float ps[2], rsum[2];
#pragma unroll
      for (int t = 0; t < 2; t++) {
        const int mq = myq0 + t * 16;
        float tm = -1e30f;
#pragma unroll
        for (int ck = 0; ck < 4; ck++) {
#pragma unroll
          for (int r = 0; r < 4; r++) {
            float v = sc[t][ck][r];
            if (diag && (kbase + ck * 16 + lg * 4 + r) > mq) v = -1e30f;
            sc[t][ck][r] = v;
            tm = fmaxf(tm, v);
          }
        }
        tm = fmaxf(tm, __shfl_xor(tm, 16));
        tm = fmaxf(tm, __shfl_xor(tm, 32));
        const float mnew = fmaxf(m[t], tm);
        ps[t] = __expf(m[t] - mnew);
        m[t] = mnew;
        float rs = 0.f;
#pragma unroll
        for (int ck = 0; ck < 4; ck++)
#pragma unroll
          for (int r = 0; r < 4; r++) {
            const float pv = __expf(sc[t][ck][r] - mnew);
            sc[t][ck][r] = pv;
            rs += pv;
          }
        rsum[t] = rs;
      }
#pragma unroll
      for (int t = 0; t < 2; t++) {
        float rs = rsum[t];
        rs += __shfl_xor(rs, 16);
        rs += __shfl_xor(rs, 32);
        l[t] = l[t] * ps[t] + rs;
#pragma unroll
        for (int sub = 0; sub < 8; sub++)
#pragma unroll
          for (int r = 0; r < 4; r++) o[t][sub][r] *= ps[t];
#pragma unroll
        for (int ck = 0; ck < 4; ck++) {
          ushort4v pk;
#pragma unroll
          for (int r = 0; r < 4; r++) pk[r] = f2bf(sc[t][ck][r]);
          *reinterpret_cast<ushort4v*>(&P[wave][t][lr][ck * 16 + lg * 4]) = pk;
        }
      }

      // PV kk=0
      __builtin_amdgcn_s_setprio(1);
#pragma unroll
      for (int t = 0; t < 2; t++) {
        const bf16x8 pf = *reinterpret_cast<const bf16x8*>(&P[wave][t][lr][lg * 8]);
#pragma unroll
        for (int sub = 0; sub < 8; sub++)
          o[t][sub] = mfma16(vf[sub], pf, o[t][sub]);
      }
      __builtin_amdgcn_s_setprio(0);
      // V^T kk=1, PV kk=1
#pragma unroll
      for (int sub = 0; sub < 8; sub++)
        vf[sub] = *reinterpret_cast<const bf16x8*>(
            vfp + ((size_t)((kt * 2 + 1) * 8 + sub) << 9) + (lane << 3));
      __builtin_amdgcn_s_setprio(1);
#pragma unroll
      for (int t = 0; t < 2; t++) {
        const bf16x8 pf = *reinterpret_cast<const bf16x8*>(&P[wave][t][lr][32 + lg * 8]);
#pragma unroll
        for (int sub = 0; sub < 8; sub++)
          o[t][sub] = mfma16(vf[sub], pf, o[t][sub]);
      }
      __builtin_amdgcn_s_setprio(0);
    }

    // publish normalized partials (ALL waves)
#pragma unroll
    for (int t = 0; t < 2; t++) {
      const float inv = (l[t] > 0.f) ? 1.0f / l[t] : 0.f;
#pragma unroll
      for (int sub = 0; sub < 8; sub++) {
        ushort4v pk;
#pragma unroll
        for (int r = 0; r < 4; r++) pk[r] = f2bf(o[t][sub][r] * inv);
        *reinterpret_cast<ushort4v*>(&Xo[wave][t * 16 + lr][sub * 16 + lg * 4]) = pk;
      }
      if (lg == 0) { Xml[wave][t * 16 + lr][0] = m[t]; Xml[wave][t * 16 + lr][1] = l[t]; }
    }
    __syncthreads();

    // 4-way merge: wave handles rows [wave*8, wave*8+8); each thread merges
    // 16 d-values (two 8-elem chunks) -> full 128-column coverage (R11 fix).
    {
      const int mrow = wave * 8 + (lane >> 3);   // 0..31 within tile
      float mm[4], ll[4];
      float ms = -1e30f;
#pragma unroll
      for (int w = 0; w < 4; w++) {
        mm[w] = Xml[w][mrow][0]; ll[w] = Xml[w][mrow][1];
        ms = fmaxf(ms, mm[w]);
      }
      float c[4], csum = 0.f;
#pragma unroll
      for (int w = 0; w < 4; w++) { c[w] = __expf(mm[w] - ms) * ll[w]; csum += c[w]; }
      const float invT = 1.0f / csum;   // csum>0: diagonal guarantees l>0 somewhere
#pragma unroll
      for (int half = 0; half < 2; half++) {
        const int dc = (lane & 7) + half * 8;    // 16 chunks of 8 -> d = dc*8..dc*8+7
        float acc[8] = {};
#pragma unroll
        for (int w = 0; w < 4; w++) {
          const ushort8 v = *reinterpret_cast<const ushort8*>(&Xo[w][mrow][dc * 8]);
#pragma unroll
          for (int e = 0; e < 8; e++) acc[e] += c[w] * bf2f(v[e]);
        }
        ushort8 outv;
#pragma unroll
        for (int e = 0; e < 8; e++) outv[e] = f2bf(acc[e] * invT);
        *reinterpret_cast<ushort8*>(
            att + (size_t)(b * SS_ + rt * 32 + mrow) * (NH_ * VD_) + h * VD_ + dc * 8) = outv;
      }
    }
    __syncthreads();  // Xo/Xml safe to overwrite in next phase
  }
}

// ---------------- launcher ----------------

extern "C" void kernel_launch(void* const* d_in, const int* in_sizes, int n_in,
                              void* d_out, int out_size, void* d_ws, size_t ws_size,
                              hipStream_t stream) {
  const float* x    = (const float*)d_in[0];
  const float* pe   = (const float*)d_in[3];
  const float* wq_w = (const float*)d_in[4];
  const float* wq_b = (const float*)d_in[5];
  const float* wk_w = (const float*)d_in[6];
  const float* wk_b = (const float*)d_in[7];
  const float* wv_w = (const float*)d_in[8];
  const float* wv_b = (const float*)d_in[9];
  const float* wo_w = (const float*)d_in[10];
  const float* wo_b = (const float*)d_in[11];
  float* out = (float*)d_out;

  char* ws = (char*)d_ws;
  unsigned short* x_bf   = (unsigned short*)(ws);                 // 4 MB
  unsigned short* wqkv_t = (unsigned short*)(ws + 4194304);       // 3 MB
  unsigned short* wo_t   = (unsigned short*)(ws + 7340032);       // 1 MB
  float*          qkv_b  = (float*)(ws + 8388608);                // 12 KB
  unsigned short* qb     = (unsigned short*)(ws + 8400896);       // 8 MB (Qf)
  unsigned short* kb     = (unsigned short*)(ws + 16789504);      // 8 MB (Kf)
  unsigned short* vtb    = (unsigned short*)(ws + 25178112);      // 8 MB (Vf)
  unsigned short* attb   = (unsigned short*)(ws + 33566720);      // 8 MB

  k_convert_x<<<2048, 256, 0, stream>>>(x, x_bf, (4096 * 512) / 4);
  {
    dim3 gt(16, 8);  // C=1024, R=512
    k_transpose_cvt<<<gt, 256, 0, stream>>>(wq_w, wqkv_t, 512, 1024);
    k_transpose_cvt<<<gt, 256, 0, stream>>>(wk_w, wqkv_t + 1024 * 512, 512, 1024);
    k_transpose_cvt<<<gt, 256, 0, stream>>>(wv_w, wqkv_t + 2048 * 512, 512, 1024);
    dim3 gt2(8, 16);  // C=512, R=1024
    k_transpose_cvt<<<gt2, 256, 0, stream>>>(wo_w, wo_t, 1024, 512);
  }
  k_concat_bias<<<12, 256, 0, stream>>>(wq_b, wk_b, wv_b, qkv_b);

  dim3 g1(24, 32);
  k_gemm_bt<0><<<g1, 256, 0, stream>>>(x_bf, wqkv_t, qkv_b, 512, qb, kb, vtb, nullptr);

  dim3 g2(NH_, 32, BB_);  // x=head -> XCD = head; uniform-work blocks
  k_attn<<<g2, 256, 0, stream>>>(qb, kb, vtb, pe, attb);

  dim3 g3(4, 32);
  k_gemm_bt<1><<<g3, 256, 0, stream>>>(attb, wo_t, wo_b, 1024, nullptr, nullptr, nullptr, out);
}